// Round 9
// baseline (435.037 us; speedup 1.0000x reference)
//
#include <hip/hip_runtime.h>
#include <hip/hip_fp16.h>

#define N_NODES 50000
#define N_EDGES 1600000
#define F_IN    128
#define EMB     48
#define HID     48
#define OUTF    64
#define KCH     7

#define NR    4                      // node ranges (LDS partitions)
#define RANGE (N_NODES / NR)         // 12500 counters
#define BPR   64                     // edge slices
#define SLICE (N_EDGES / BPR)        // 25000 edges per slice (div by 4)
#define HTHREADS 512
#define NBLK  ((N_NODES + 255) / 256)   // 196 reduce blocks

// ---- pass A: partitioned LDS histogram (cnt by col packed u16, deg by row f32) ----
__global__ __launch_bounds__(HTHREADS) void hist_part_kernel(
    const int* __restrict__ row, const int* __restrict__ col,
    const float* __restrict__ w,
    unsigned short* __restrict__ pc, float* __restrict__ pd)
{
    __shared__ unsigned lc32[RANGE / 2];  // 25 KB, 2 u16 counters per word
    __shared__ float    ld[RANGE];        // 50 KB
    int t = threadIdx.x;
    for (int i = t; i < RANGE / 2; i += HTHREADS) lc32[i] = 0u;
    for (int i = t; i < RANGE; i += HTHREADS) ld[i] = 0.f;
    __syncthreads();
    int r = blockIdx.x / BPR;        // node range
    int b = blockIdx.x % BPR;        // edge slice
    int base = r * RANGE;
    int lo = b * SLICE;
    for (int e0 = lo + t * 4; e0 < lo + SLICE; e0 += HTHREADS * 4) {
        int4   c4 = *(const int4*)&col[e0];
        int4   r4 = *(const int4*)&row[e0];
        float4 w4 = *(const float4*)&w[e0];
        int ci, ri;
        ci = c4.x - base; if ((unsigned)ci < RANGE) atomicAdd(&lc32[ci >> 1], 1u << ((ci & 1) * 16));
        ri = r4.x - base; if ((unsigned)ri < RANGE) atomicAdd(&ld[ri], w4.x);
        ci = c4.y - base; if ((unsigned)ci < RANGE) atomicAdd(&lc32[ci >> 1], 1u << ((ci & 1) * 16));
        ri = r4.y - base; if ((unsigned)ri < RANGE) atomicAdd(&ld[ri], w4.y);
        ci = c4.z - base; if ((unsigned)ci < RANGE) atomicAdd(&lc32[ci >> 1], 1u << ((ci & 1) * 16));
        ri = r4.z - base; if ((unsigned)ri < RANGE) atomicAdd(&ld[ri], w4.z);
        ci = c4.w - base; if ((unsigned)ci < RANGE) atomicAdd(&lc32[ci >> 1], 1u << ((ci & 1) * 16));
        ri = r4.w - base; if ((unsigned)ri < RANGE) atomicAdd(&ld[ri], w4.w);
    }
    __syncthreads();
    unsigned short* pcb = pc + (size_t)blockIdx.x * RANGE;
    float*          pdb = pd + (size_t)blockIdx.x * RANGE;
    for (int i = t; i < RANGE; i += HTHREADS) {
        pcb[i] = (unsigned short)((lc32[i >> 1] >> ((i & 1) * 16)) & 0xFFFFu);
        pdb[i] = ld[i];
    }
}

// ---- fold partials: dinv, per-slice prefix (pc in place), AND intra-block
//      exclusive scan of node counts -> off (local), block totals -> bsum ----
__global__ __launch_bounds__(256) void reduce_kernel(
    unsigned short* __restrict__ pc, const float* __restrict__ pd,
    float* __restrict__ dinv, int* __restrict__ off, int* __restrict__ bsum)
{
    int t = threadIdx.x;
    int n = blockIdx.x * 256 + t;
    int c = 0; float d = 0.f;
    if (n < N_NODES) {
        int r = n / RANGE, i = n - r * RANGE;
        size_t base = (size_t)r * BPR * RANGE + i;
        unsigned csum = 0;
        for (int b = 0; b < BPR; ++b) {
            size_t idx = base + (size_t)b * RANGE;
            unsigned x = pc[idx];
            pc[idx] = (unsigned short)csum;
            csum += x;
            d += pd[idx];
        }
        c = (int)csum;
        dinv[n] = d > 0.f ? rsqrtf(d) : 0.f;
    }
    // intra-block exclusive scan of c
    int lane = t & 63, wid = t >> 6;
    int v = c;
    for (int s = 1; s < 64; s <<= 1) {
        int u = __shfl_up(v, s);
        if (lane >= s) v += u;
    }
    __shared__ int ws[4];
    if (lane == 63) ws[wid] = v;
    __syncthreads();
    int wb = 0;
    for (int i = 0; i < 4; ++i) if (i < wid) wb += ws[i];
    int ex = (v - c) + wb;
    if (n < N_NODES) off[n] = ex;
    if (t == 255) bsum[blockIdx.x] = ex + c;
}

// ---- exclusive scan of 196 block sums (tiny, 1 block) ----
__global__ __launch_bounds__(256) void bsum_scan_kernel(
    int* __restrict__ bsum, int* __restrict__ off)
{
    int t = threadIdx.x;
    int orig = (t < NBLK) ? bsum[t] : 0;
    int lane = t & 63, wid = t >> 6;
    int v = orig;
    for (int s = 1; s < 64; s <<= 1) {
        int u = __shfl_up(v, s);
        if (lane >= s) v += u;
    }
    __shared__ int ws[4];
    if (lane == 63) ws[wid] = v;
    __syncthreads();
    int wb = 0;
    for (int i = 0; i < 4; ++i) if (i < wid) wb += ws[i];
    int ex = (v - orig) + wb;
    if (t < NBLK) bsum[t] = ex;
    if (t == NBLK - 1) off[N_NODES] = ex + orig;
}

// ---- add block prefix back: off[n] += bsum[n/256] ----
__global__ __launch_bounds__(256) void add_off_kernel(
    int* __restrict__ off, const int* __restrict__ bsum)
{
    int n = blockIdx.x * 256 + threadIdx.x;
    if (n < N_NODES) off[n] += bsum[n >> 8];
}

// ---- pass D: scatter via re-derived LDS ranks — zero global atomics ----
__global__ __launch_bounds__(HTHREADS) void scatter_part_kernel(
    const int* __restrict__ row, const int* __restrict__ col,
    const float* __restrict__ w, const float* __restrict__ dinv,
    const int* __restrict__ off, const unsigned short* __restrict__ pc,
    uint2* __restrict__ edges)
{
    __shared__ unsigned lc32[RANGE / 2];  // 25 KB
    int t = threadIdx.x;
    for (int i = t; i < RANGE / 2; i += HTHREADS) lc32[i] = 0u;
    __syncthreads();
    int r = blockIdx.x / BPR;
    int b = blockIdx.x % BPR;
    int base = r * RANGE;
    int lo = b * SLICE;
    const unsigned short* pcb = pc + (size_t)blockIdx.x * RANGE;
    for (int e0 = lo + t * 4; e0 < lo + SLICE; e0 += HTHREADS * 4) {
        int4   c4 = *(const int4*)&col[e0];
        int4   r4 = *(const int4*)&row[e0];
        float4 w4 = *(const float4*)&w[e0];
        #pragma unroll
        for (int j = 0; j < 4; ++j) {
            int c  = (j == 0) ? c4.x : (j == 1) ? c4.y : (j == 2) ? c4.z : c4.w;
            int rw = (j == 0) ? r4.x : (j == 1) ? r4.y : (j == 2) ? r4.z : r4.w;
            float we = (j == 0) ? w4.x : (j == 1) ? w4.y : (j == 2) ? w4.z : w4.w;
            int ci = c - base;
            if ((unsigned)ci < RANGE) {
                unsigned old = atomicAdd(&lc32[ci >> 1], 1u << ((ci & 1) * 16));
                unsigned lrank = (old >> ((ci & 1) * 16)) & 0xFFFFu;
                float nr = -dinv[rw] * we * dinv[c];
                int pos = off[c] + (int)pcb[ci] + (int)lrank;
                edges[pos] = make_uint2((unsigned)rw, __float_as_uint(nr));
            }
        }
    }
}

// ---- xf = relu(x @ W_in + b_in) -> f32 d_out tail AND fp16 T0 (float4 x loads) ----
__global__ __launch_bounds__(256) void xf_kernel(
    const float* __restrict__ x, const float* __restrict__ Win,
    const float* __restrict__ bin, float* __restrict__ xf_out,
    __half* __restrict__ T0h)
{
    __shared__ float Ws[F_IN * EMB];   // 24576 B
    int t = threadIdx.x;
    for (int i = t; i < F_IN * EMB; i += 256) Ws[i] = Win[i];
    __syncthreads();
    int gid = blockIdx.x * 256 + t;
    if (gid >= N_NODES * EMB) return;
    int n = gid / EMB, j = gid - n * EMB;
    const float4* xr4 = reinterpret_cast<const float4*>(x + (size_t)n * F_IN);
    float acc = bin[j];
#pragma unroll 8
    for (int k4 = 0; k4 < F_IN / 4; ++k4) {
        float4 xv = xr4[k4];
        const float* wk = &Ws[(k4 * 4) * EMB + j];
        acc += xv.x * wk[0] + xv.y * wk[EMB] + xv.z * wk[2 * EMB] + xv.w * wk[3 * EMB];
    }
    acc = fmaxf(acc, 0.f);
    xf_out[gid] = acc;
    T0h[gid] = __float2half_rn(acc);
}

// ---- out_acc = T0 @ W0 (write, k=0 term; reads exact f32 xf) ----
__global__ __launch_bounds__(256) void gemm48_write_kernel(
    const float* __restrict__ T, const float* __restrict__ W,
    float* __restrict__ out)
{
    __shared__ float Ws[EMB * HID];
    int t = threadIdx.x;
    for (int i = t; i < EMB * HID; i += 256) Ws[i] = W[i];
    __syncthreads();
    int gid = blockIdx.x * 256 + t;
    if (gid >= N_NODES * HID) return;
    int n = gid / HID, j = gid - n * HID;
    const float* tr = T + (size_t)n * EMB;
    float acc = 0.f;
#pragma unroll 8
    for (int c = 0; c < EMB; ++c) acc += tr[c] * Ws[c * HID + j];
    out[gid] = acc;
}

// ---- fused: T_k = prop (or 2*prop - tprev) in fp16, out_acc += T_k @ W_k ----
// 16 lanes/node; lane owns features (2l, 2l+1, 32+l): one aligned __half2 +
// one __half load per edge (2 loads vs 3). Unroll x8 for MLP.
__global__ __launch_bounds__(256) void prop_fused_kernel(
    const int* __restrict__ off, const uint2* __restrict__ edges,
    const __half* __restrict__ tsrc, const __half* __restrict__ tprev,
    __half* __restrict__ tdst, const float* __restrict__ Wk,
    float* __restrict__ out_acc, int cheb_mode)
{
    __shared__ float Ws[EMB * HID];     // 9216 B
    __shared__ float tdS[16][EMB + 1];
    int t = threadIdx.x;
    for (int i = t; i < EMB * HID; i += 256) Ws[i] = Wk[i];

    int grp = t >> 4, lane = t & 15;
    int g = blockIdx.x * 16 + grp;

    float a0 = 0.f, a1 = 0.f, a2 = 0.f;
    int s = off[g], e = off[g + 1];
    int p = s;
    int e8 = s + ((e - s) & ~7);
    for (; p < e8; p += 8) {
        uint2 er[8];
        #pragma unroll
        for (int j = 0; j < 8; ++j) er[j] = edges[p + j];
        float ww[8]; __half2 h01[8]; __half h2[8];
        #pragma unroll
        for (int j = 0; j < 8; ++j) {
            const __half* tj = tsrc + (size_t)er[j].x * EMB;
            ww[j] = __uint_as_float(er[j].y);
            h01[j] = *reinterpret_cast<const __half2*>(tj + 2 * lane);
            h2[j]  = tj[32 + lane];
        }
        #pragma unroll
        for (int j = 0; j < 8; ++j) {
            a0 += ww[j] * __low2float(h01[j]);
            a1 += ww[j] * __high2float(h01[j]);
            a2 += ww[j] * __half2float(h2[j]);
        }
    }
    for (; p < e; ++p) {
        uint2 er = edges[p];
        float wv = __uint_as_float(er.y);
        const __half* tr = tsrc + (size_t)er.x * EMB;
        __half2 h01 = *reinterpret_cast<const __half2*>(tr + 2 * lane);
        a0 += wv * __low2float(h01);
        a1 += wv * __high2float(h01);
        a2 += wv * __half2float(tr[32 + lane]);
    }
    if (cheb_mode) {
        const __half* tp = tprev + (size_t)g * EMB;
        __half2 tp01 = *reinterpret_cast<const __half2*>(tp + 2 * lane);
        a0 = 2.f * a0 - __low2float(tp01);
        a1 = 2.f * a1 - __high2float(tp01);
        a2 = 2.f * a2 - __half2float(tp[32 + lane]);
    }
    __half* td = tdst + (size_t)g * EMB;
    __half2 hw; hw.x = __float2half_rn(a0); hw.y = __float2half_rn(a1);
    *reinterpret_cast<__half2*>(td + 2 * lane) = hw;
    td[32 + lane] = __float2half_rn(a2);
    tdS[grp][2 * lane]     = a0;
    tdS[grp][2 * lane + 1] = a1;
    tdS[grp][32 + lane]    = a2;
    __syncthreads();

    float o0 = 0.f, o1 = 0.f, o2 = 0.f;
#pragma unroll 8
    for (int c = 0; c < EMB; ++c) {
        float tv = tdS[grp][c];
        o0 += tv * Ws[c * HID + lane];
        o1 += tv * Ws[c * HID + lane + 16];
        o2 += tv * Ws[c * HID + lane + 32];
    }
    float* orow = out_acc + (size_t)g * HID;
    orow[lane]      += o0;
    orow[lane + 16] += o1;
    orow[lane + 32] += o2;
}

// ---- y = relu(out_acc + b_cheb) @ W_out + b_out ----
__global__ __launch_bounds__(256) void final_kernel(
    const float* __restrict__ out_acc, const float* __restrict__ bch,
    const float* __restrict__ Wout, const float* __restrict__ bout,
    float* __restrict__ y)
{
    __shared__ float Ws[HID * OUTF];
    __shared__ float bs[HID];
    int t = threadIdx.x;
    for (int i = t; i < HID * OUTF; i += 256) Ws[i] = Wout[i];
    if (t < HID) bs[t] = bch[t];
    __syncthreads();
    int gid = blockIdx.x * 256 + t;
    if (gid >= N_NODES * OUTF) return;
    int n = gid / OUTF, o = gid - n * OUTF;
    const float* orow = out_acc + (size_t)n * HID;
    float acc = bout[o];
#pragma unroll 8
    for (int h = 0; h < HID; ++h) {
        float v = fmaxf(orow[h] + bs[h], 0.f);
        acc += v * Ws[h * OUTF + o];
    }
    y[gid] = acc;
}

extern "C" void kernel_launch(void* const* d_in, const int* in_sizes, int n_in,
                              void* d_out, int out_size, void* d_ws, size_t ws_size,
                              hipStream_t stream)
{
    const float* x    = (const float*)d_in[0];
    const int*   ei   = (const int*)d_in[1];
    const float* ew   = (const float*)d_in[2];
    const float* Win  = (const float*)d_in[3];
    const float* bin  = (const float*)d_in[4];
    const float* Wch  = (const float*)d_in[5];   // [7,48,48]
    const float* bch  = (const float*)d_in[6];
    const float* Wout = (const float*)d_in[7];
    const float* bout = (const float*)d_in[8];

    const int* row = ei;
    const int* col = ei + N_EDGES;

    float* y_out  = (float*)d_out;                           // [N,64]
    float* xf_out = (float*)d_out + (size_t)N_NODES * OUTF;  // [N,48]

    // ---- workspace carve (256B aligned); every buffer fully written before read ----
    char* p = (char*)d_ws;
    auto carve = [&](size_t bytes) {
        void* q = p;
        p += (bytes + 255) & ~(size_t)255;
        return q;
    };
    unsigned short* pc = (unsigned short*)carve((size_t)NR * BPR * RANGE * 2); // 6.4 MB
    float*    pd  = (float*)carve((size_t)NR * BPR * RANGE * 4);               // 12.8 MB
    float*    dinv = (float*)carve(N_NODES * 4);
    int*      off  = (int*)  carve((N_NODES + 1) * 4);
    int*      bsum = (int*)  carve(NBLK * 4);
    uint2*    edges = (uint2*)carve((size_t)N_EDGES * 8);
    float*    out_acc = (float*)carve((size_t)N_NODES * HID * 4);
    __half*   T0h = (__half*)carve((size_t)N_NODES * EMB * 2);
    __half*   TAh = (__half*)carve((size_t)N_NODES * EMB * 2);
    __half*   TBh = (__half*)carve((size_t)N_NODES * EMB * 2);
    __half*   TCh = (__half*)carve((size_t)N_NODES * EMB * 2);

    // graph preprocessing — zero global atomics, hierarchical scan
    hist_part_kernel<<<NR * BPR, HTHREADS, 0, stream>>>(row, col, ew, pc, pd);
    reduce_kernel<<<NBLK, 256, 0, stream>>>(pc, pd, dinv, off, bsum);
    bsum_scan_kernel<<<1, 256, 0, stream>>>(bsum, off);
    add_off_kernel<<<NBLK, 256, 0, stream>>>(off, bsum);
    scatter_part_kernel<<<NR * BPR, HTHREADS, 0, stream>>>(row, col, ew, dinv, off, pc, edges);

    // xf = relu(x @ W_in + b_in) -> f32 d_out tail + fp16 T0
    xf_kernel<<<(N_NODES * EMB + 255) / 256, 256, 0, stream>>>(x, Win, bin, xf_out, T0h);

    // out_acc = T0 @ W0 (exact f32)
    gemm48_write_kernel<<<(N_NODES * HID + 255) / 256, 256, 0, stream>>>(xf_out, Wch, out_acc);

    const int prop_grid = N_NODES / 16;   // 3125, exact

    // T1 = prop(T0); out_acc += T1 @ W1
    prop_fused_kernel<<<prop_grid, 256, 0, stream>>>(off, edges, T0h, nullptr,
                                                     TAh, Wch + EMB * HID, out_acc, 0);
    // Chebyshev recursion with fused GEMM — proven 3-buffer rotation.
    const __half* A = T0h;  // T_{k-2}
    __half*       B = TAh;  // T_{k-1}
    __half* bufs[3] = {TBh, TCh, TAh};
    for (int k = 2; k < KCH; ++k) {
        __half* C = bufs[(k - 2) % 3];
        prop_fused_kernel<<<prop_grid, 256, 0, stream>>>(off, edges, B, A,
                                                         C, Wch + (size_t)k * EMB * HID, out_acc, 1);
        A = B; B = C;
    }

    // y = relu(out_acc + b_cheb) @ W_out + b_out
    final_kernel<<<(N_NODES * OUTF + 255) / 256, 256, 0, stream>>>(out_acc, bch, Wout, bout, y_out);
}

// Round 10
// 416.766 us; speedup vs baseline: 1.0438x; 1.0438x over previous
//
#include <hip/hip_runtime.h>
#include <hip/hip_fp16.h>

#define N_NODES 50000
#define N_EDGES 1600000
#define F_IN    128
#define EMB     48
#define HID     48
#define OUTF    64
#define KCH     7

#define NR    8                      // node ranges (LDS partitions)
#define RANGE (N_NODES / NR)         // 6250 counters
#define BPR   64                     // edge slices
#define SLICE (N_EDGES / BPR)        // 25000 edges per slice (div by 4)
#define HTHREADS 512
#define NBLK  ((N_NODES + 255) / 256)   // 196 reduce blocks
#define XNPB  16                     // nodes per xf block

// ---- pass A: partitioned LDS histogram (cnt by col packed u16, deg by row f32) ----
__global__ __launch_bounds__(HTHREADS) void hist_part_kernel(
    const int* __restrict__ row, const int* __restrict__ col,
    const float* __restrict__ w,
    unsigned short* __restrict__ pc, float* __restrict__ pd)
{
    __shared__ unsigned lc32[RANGE / 2];  // 12.5 KB, 2 u16 counters per word
    __shared__ float    ld[RANGE];        // 25 KB
    int t = threadIdx.x;
    for (int i = t; i < RANGE / 2; i += HTHREADS) lc32[i] = 0u;
    for (int i = t; i < RANGE; i += HTHREADS) ld[i] = 0.f;
    __syncthreads();
    int r = blockIdx.x / BPR;        // node range
    int b = blockIdx.x % BPR;        // edge slice
    int base = r * RANGE;
    int lo = b * SLICE;
    for (int e0 = lo + t * 4; e0 < lo + SLICE; e0 += HTHREADS * 4) {
        int4   c4 = *(const int4*)&col[e0];
        int4   r4 = *(const int4*)&row[e0];
        float4 w4 = *(const float4*)&w[e0];
        int ci, ri;
        ci = c4.x - base; if ((unsigned)ci < RANGE) atomicAdd(&lc32[ci >> 1], 1u << ((ci & 1) * 16));
        ri = r4.x - base; if ((unsigned)ri < RANGE) atomicAdd(&ld[ri], w4.x);
        ci = c4.y - base; if ((unsigned)ci < RANGE) atomicAdd(&lc32[ci >> 1], 1u << ((ci & 1) * 16));
        ri = r4.y - base; if ((unsigned)ri < RANGE) atomicAdd(&ld[ri], w4.y);
        ci = c4.z - base; if ((unsigned)ci < RANGE) atomicAdd(&lc32[ci >> 1], 1u << ((ci & 1) * 16));
        ri = r4.z - base; if ((unsigned)ri < RANGE) atomicAdd(&ld[ri], w4.z);
        ci = c4.w - base; if ((unsigned)ci < RANGE) atomicAdd(&lc32[ci >> 1], 1u << ((ci & 1) * 16));
        ri = r4.w - base; if ((unsigned)ri < RANGE) atomicAdd(&ld[ri], w4.w);
    }
    __syncthreads();
    unsigned short* pcb = pc + (size_t)blockIdx.x * RANGE;
    float*          pdb = pd + (size_t)blockIdx.x * RANGE;
    for (int i = t; i < RANGE; i += HTHREADS) {
        pcb[i] = (unsigned short)((lc32[i >> 1] >> ((i & 1) * 16)) & 0xFFFFu);
        pdb[i] = ld[i];
    }
}

// ---- fold partials: dinv, per-slice prefix (pc in place), AND intra-block
//      exclusive scan of node counts -> off (local), block totals -> bsum ----
__global__ __launch_bounds__(256) void reduce_kernel(
    unsigned short* __restrict__ pc, const float* __restrict__ pd,
    float* __restrict__ dinv, int* __restrict__ off, int* __restrict__ bsum)
{
    int t = threadIdx.x;
    int n = blockIdx.x * 256 + t;
    int c = 0; float d = 0.f;
    if (n < N_NODES) {
        int r = n / RANGE, i = n - r * RANGE;
        size_t base = (size_t)r * BPR * RANGE + i;
        unsigned csum = 0;
        for (int b = 0; b < BPR; ++b) {
            size_t idx = base + (size_t)b * RANGE;
            unsigned x = pc[idx];
            pc[idx] = (unsigned short)csum;
            csum += x;
            d += pd[idx];
        }
        c = (int)csum;
        dinv[n] = d > 0.f ? rsqrtf(d) : 0.f;
    }
    // intra-block exclusive scan of c
    int lane = t & 63, wid = t >> 6;
    int v = c;
    for (int s = 1; s < 64; s <<= 1) {
        int u = __shfl_up(v, s);
        if (lane >= s) v += u;
    }
    __shared__ int ws[4];
    if (lane == 63) ws[wid] = v;
    __syncthreads();
    int wb = 0;
    for (int i = 0; i < 4; ++i) if (i < wid) wb += ws[i];
    int ex = (v - c) + wb;
    if (n < N_NODES) off[n] = ex;
    if (t == 255) bsum[blockIdx.x] = ex + c;
}

// ---- exclusive scan of 196 block sums (tiny, 1 block) ----
__global__ __launch_bounds__(256) void bsum_scan_kernel(
    int* __restrict__ bsum, int* __restrict__ off)
{
    int t = threadIdx.x;
    int orig = (t < NBLK) ? bsum[t] : 0;
    int lane = t & 63, wid = t >> 6;
    int v = orig;
    for (int s = 1; s < 64; s <<= 1) {
        int u = __shfl_up(v, s);
        if (lane >= s) v += u;
    }
    __shared__ int ws[4];
    if (lane == 63) ws[wid] = v;
    __syncthreads();
    int wb = 0;
    for (int i = 0; i < 4; ++i) if (i < wid) wb += ws[i];
    int ex = (v - orig) + wb;
    if (t < NBLK) bsum[t] = ex;
    if (t == NBLK - 1) off[N_NODES] = ex + orig;
}

// ---- add block prefix back: off[n] += bsum[n/256] ----
__global__ __launch_bounds__(256) void add_off_kernel(
    int* __restrict__ off, const int* __restrict__ bsum)
{
    int n = blockIdx.x * 256 + threadIdx.x;
    if (n < N_NODES) off[n] += bsum[n >> 8];
}

// ---- pass D: scatter via re-derived LDS ranks — zero global atomics ----
__global__ __launch_bounds__(HTHREADS) void scatter_part_kernel(
    const int* __restrict__ row, const int* __restrict__ col,
    const float* __restrict__ w, const float* __restrict__ dinv,
    const int* __restrict__ off, const unsigned short* __restrict__ pc,
    uint2* __restrict__ edges)
{
    __shared__ unsigned lc32[RANGE / 2];  // 12.5 KB
    int t = threadIdx.x;
    for (int i = t; i < RANGE / 2; i += HTHREADS) lc32[i] = 0u;
    __syncthreads();
    int r = blockIdx.x / BPR;
    int b = blockIdx.x % BPR;
    int base = r * RANGE;
    int lo = b * SLICE;
    const unsigned short* pcb = pc + (size_t)blockIdx.x * RANGE;
    for (int e0 = lo + t * 4; e0 < lo + SLICE; e0 += HTHREADS * 4) {
        int4   c4 = *(const int4*)&col[e0];
        int4   r4 = *(const int4*)&row[e0];
        float4 w4 = *(const float4*)&w[e0];
        #pragma unroll
        for (int j = 0; j < 4; ++j) {
            int c  = (j == 0) ? c4.x : (j == 1) ? c4.y : (j == 2) ? c4.z : c4.w;
            int rw = (j == 0) ? r4.x : (j == 1) ? r4.y : (j == 2) ? r4.z : r4.w;
            float we = (j == 0) ? w4.x : (j == 1) ? w4.y : (j == 2) ? w4.z : w4.w;
            int ci = c - base;
            if ((unsigned)ci < RANGE) {
                unsigned old = atomicAdd(&lc32[ci >> 1], 1u << ((ci & 1) * 16));
                unsigned lrank = (old >> ((ci & 1) * 16)) & 0xFFFFu;
                float nr = -dinv[rw] * we * dinv[c];
                int pos = off[c] + (int)pcb[ci] + (int)lrank;
                edges[pos] = make_uint2((unsigned)rw, __float_as_uint(nr));
            }
        }
    }
}

// ---- fused xf + k=0 GEMM: xf = relu(x@W_in+b), out_acc = xf@Wch0 ----
// 16 nodes/block; x staged in padded LDS once (coalesced); 16-lane groups,
// lane owns outputs {l, l+16, l+32}; W reads are broadcast/conflict-free.
__global__ __launch_bounds__(256) void xf_fused_kernel(
    const float* __restrict__ x, const float* __restrict__ Win,
    const float* __restrict__ bin, const float* __restrict__ Wch0,
    float* __restrict__ xf_out, __half* __restrict__ T0h,
    float* __restrict__ out_acc)
{
    __shared__ float Ws[F_IN * EMB];       // 24576 B
    __shared__ float W0s[EMB * HID];       // 9216 B
    __shared__ float xs[XNPB][F_IN + 1];   // 8256 B (pad kills grp-bank alias)
    __shared__ float xfS[XNPB][EMB + 1];   // 3136 B
    int t = threadIdx.x;
    for (int i = t; i < F_IN * EMB; i += 256) Ws[i] = Win[i];
    for (int i = t; i < EMB * HID; i += 256) W0s[i] = Wch0[i];
    int n0 = blockIdx.x * XNPB;
    for (int i = t; i < XNPB * (F_IN / 4); i += 256) {
        int ln = i >> 5, k4 = i & 31;     // F_IN/4 == 32
        float4 v = reinterpret_cast<const float4*>(x + (size_t)(n0 + ln) * F_IN)[k4];
        xs[ln][k4 * 4 + 0] = v.x; xs[ln][k4 * 4 + 1] = v.y;
        xs[ln][k4 * 4 + 2] = v.z; xs[ln][k4 * 4 + 3] = v.w;
    }
    __syncthreads();
    int grp = t >> 4, lane = t & 15;
    float a0 = bin[lane], a1 = bin[lane + 16], a2 = bin[lane + 32];
#pragma unroll 4
    for (int k = 0; k < F_IN; ++k) {
        float xv = xs[grp][k];
        const float* wk = &Ws[k * EMB];
        a0 += xv * wk[lane];
        a1 += xv * wk[lane + 16];
        a2 += xv * wk[lane + 32];
    }
    a0 = fmaxf(a0, 0.f); a1 = fmaxf(a1, 0.f); a2 = fmaxf(a2, 0.f);
    int g = n0 + grp;
    float* xo = xf_out + (size_t)g * EMB;
    xo[lane] = a0; xo[lane + 16] = a1; xo[lane + 32] = a2;
    __half* th = T0h + (size_t)g * EMB;
    th[lane] = __float2half_rn(a0);
    th[lane + 16] = __float2half_rn(a1);
    th[lane + 32] = __float2half_rn(a2);
    xfS[grp][lane] = a0; xfS[grp][lane + 16] = a1; xfS[grp][lane + 32] = a2;
    __syncthreads();
    float o0 = 0.f, o1 = 0.f, o2 = 0.f;
#pragma unroll 8
    for (int c = 0; c < EMB; ++c) {
        float tv = xfS[grp][c];
        o0 += tv * W0s[c * HID + lane];
        o1 += tv * W0s[c * HID + lane + 16];
        o2 += tv * W0s[c * HID + lane + 32];
    }
    float* orow = out_acc + (size_t)g * HID;
    orow[lane] = o0; orow[lane + 16] = o1; orow[lane + 32] = o2;
}

// ---- fused: T_k = prop (or 2*prop - tprev) in fp16, out_acc += T_k @ W_k ----
// 16 lanes/node; lane owns features (2l, 2l+1, 32+l): one aligned __half2 +
// one __half load per edge. Unroll x8 for MLP.
__global__ __launch_bounds__(256) void prop_fused_kernel(
    const int* __restrict__ off, const uint2* __restrict__ edges,
    const __half* __restrict__ tsrc, const __half* __restrict__ tprev,
    __half* __restrict__ tdst, const float* __restrict__ Wk,
    float* __restrict__ out_acc, int cheb_mode)
{
    __shared__ float Ws[EMB * HID];     // 9216 B
    __shared__ float tdS[16][EMB + 1];
    int t = threadIdx.x;
    for (int i = t; i < EMB * HID; i += 256) Ws[i] = Wk[i];

    int grp = t >> 4, lane = t & 15;
    int g = blockIdx.x * 16 + grp;

    float a0 = 0.f, a1 = 0.f, a2 = 0.f;
    int s = off[g], e = off[g + 1];
    int p = s;
    int e8 = s + ((e - s) & ~7);
    for (; p < e8; p += 8) {
        uint2 er[8];
        #pragma unroll
        for (int j = 0; j < 8; ++j) er[j] = edges[p + j];
        float ww[8]; __half2 h01[8]; __half h2[8];
        #pragma unroll
        for (int j = 0; j < 8; ++j) {
            const __half* tj = tsrc + (size_t)er[j].x * EMB;
            ww[j] = __uint_as_float(er[j].y);
            h01[j] = *reinterpret_cast<const __half2*>(tj + 2 * lane);
            h2[j]  = tj[32 + lane];
        }
        #pragma unroll
        for (int j = 0; j < 8; ++j) {
            a0 += ww[j] * __low2float(h01[j]);
            a1 += ww[j] * __high2float(h01[j]);
            a2 += ww[j] * __half2float(h2[j]);
        }
    }
    for (; p < e; ++p) {
        uint2 er = edges[p];
        float wv = __uint_as_float(er.y);
        const __half* tr = tsrc + (size_t)er.x * EMB;
        __half2 h01 = *reinterpret_cast<const __half2*>(tr + 2 * lane);
        a0 += wv * __low2float(h01);
        a1 += wv * __high2float(h01);
        a2 += wv * __half2float(tr[32 + lane]);
    }
    if (cheb_mode) {
        const __half* tp = tprev + (size_t)g * EMB;
        __half2 tp01 = *reinterpret_cast<const __half2*>(tp + 2 * lane);
        a0 = 2.f * a0 - __low2float(tp01);
        a1 = 2.f * a1 - __high2float(tp01);
        a2 = 2.f * a2 - __half2float(tp[32 + lane]);
    }
    __half* td = tdst + (size_t)g * EMB;
    __half2 hw; hw.x = __float2half_rn(a0); hw.y = __float2half_rn(a1);
    *reinterpret_cast<__half2*>(td + 2 * lane) = hw;
    td[32 + lane] = __float2half_rn(a2);
    tdS[grp][2 * lane]     = a0;
    tdS[grp][2 * lane + 1] = a1;
    tdS[grp][32 + lane]    = a2;
    __syncthreads();

    float o0 = 0.f, o1 = 0.f, o2 = 0.f;
#pragma unroll 8
    for (int c = 0; c < EMB; ++c) {
        float tv = tdS[grp][c];
        o0 += tv * Ws[c * HID + lane];
        o1 += tv * Ws[c * HID + lane + 16];
        o2 += tv * Ws[c * HID + lane + 32];
    }
    float* orow = out_acc + (size_t)g * HID;
    orow[lane]      += o0;
    orow[lane + 16] += o1;
    orow[lane + 32] += o2;
}

// ---- y = relu(out_acc + b_cheb) @ W_out + b_out ----
__global__ __launch_bounds__(256) void final_kernel(
    const float* __restrict__ out_acc, const float* __restrict__ bch,
    const float* __restrict__ Wout, const float* __restrict__ bout,
    float* __restrict__ y)
{
    __shared__ float Ws[HID * OUTF];
    __shared__ float bs[HID];
    int t = threadIdx.x;
    for (int i = t; i < HID * OUTF; i += 256) Ws[i] = Wout[i];
    if (t < HID) bs[t] = bch[t];
    __syncthreads();
    int gid = blockIdx.x * 256 + t;
    if (gid >= N_NODES * OUTF) return;
    int n = gid / OUTF, o = gid - n * OUTF;
    const float* orow = out_acc + (size_t)n * HID;
    float acc = bout[o];
#pragma unroll 8
    for (int h = 0; h < HID; ++h) {
        float v = fmaxf(orow[h] + bs[h], 0.f);
        acc += v * Ws[h * OUTF + o];
    }
    y[gid] = acc;
}

extern "C" void kernel_launch(void* const* d_in, const int* in_sizes, int n_in,
                              void* d_out, int out_size, void* d_ws, size_t ws_size,
                              hipStream_t stream)
{
    const float* x    = (const float*)d_in[0];
    const int*   ei   = (const int*)d_in[1];
    const float* ew   = (const float*)d_in[2];
    const float* Win  = (const float*)d_in[3];
    const float* bin  = (const float*)d_in[4];
    const float* Wch  = (const float*)d_in[5];   // [7,48,48]
    const float* bch  = (const float*)d_in[6];
    const float* Wout = (const float*)d_in[7];
    const float* bout = (const float*)d_in[8];

    const int* row = ei;
    const int* col = ei + N_EDGES;

    float* y_out  = (float*)d_out;                           // [N,64]
    float* xf_out = (float*)d_out + (size_t)N_NODES * OUTF;  // [N,48]

    // ---- workspace carve (256B aligned); every buffer fully written before read ----
    char* p = (char*)d_ws;
    auto carve = [&](size_t bytes) {
        void* q = p;
        p += (bytes + 255) & ~(size_t)255;
        return q;
    };
    unsigned short* pc = (unsigned short*)carve((size_t)NR * BPR * RANGE * 2); // 6.4 MB
    float*    pd  = (float*)carve((size_t)NR * BPR * RANGE * 4);               // 12.8 MB
    float*    dinv = (float*)carve(N_NODES * 4);
    int*      off  = (int*)  carve((N_NODES + 1) * 4);
    int*      bsum = (int*)  carve(NBLK * 4);
    uint2*    edges = (uint2*)carve((size_t)N_EDGES * 8);
    float*    out_acc = (float*)carve((size_t)N_NODES * HID * 4);
    __half*   T0h = (__half*)carve((size_t)N_NODES * EMB * 2);
    __half*   TAh = (__half*)carve((size_t)N_NODES * EMB * 2);
    __half*   TBh = (__half*)carve((size_t)N_NODES * EMB * 2);
    __half*   TCh = (__half*)carve((size_t)N_NODES * EMB * 2);

    // graph preprocessing — zero global atomics, hierarchical scan
    hist_part_kernel<<<NR * BPR, HTHREADS, 0, stream>>>(row, col, ew, pc, pd);
    reduce_kernel<<<NBLK, 256, 0, stream>>>(pc, pd, dinv, off, bsum);
    bsum_scan_kernel<<<1, 256, 0, stream>>>(bsum, off);
    add_off_kernel<<<NBLK, 256, 0, stream>>>(off, bsum);
    scatter_part_kernel<<<NR * BPR, HTHREADS, 0, stream>>>(row, col, ew, dinv, off, pc, edges);

    // xf = relu(x @ W_in + b_in) -> f32 d_out tail + fp16 T0, AND out_acc = xf @ Wch0
    xf_fused_kernel<<<N_NODES / XNPB, 256, 0, stream>>>(x, Win, bin, Wch,
                                                        xf_out, T0h, out_acc);

    const int prop_grid = N_NODES / 16;   // 3125, exact

    // T1 = prop(T0); out_acc += T1 @ W1
    prop_fused_kernel<<<prop_grid, 256, 0, stream>>>(off, edges, T0h, nullptr,
                                                     TAh, Wch + EMB * HID, out_acc, 0);
    // Chebyshev recursion with fused GEMM — proven 3-buffer rotation.
    const __half* A = T0h;  // T_{k-2}
    __half*       B = TAh;  // T_{k-1}
    __half* bufs[3] = {TBh, TCh, TAh};
    for (int k = 2; k < KCH; ++k) {
        __half* C = bufs[(k - 2) % 3];
        prop_fused_kernel<<<prop_grid, 256, 0, stream>>>(off, edges, B, A,
                                                         C, Wch + (size_t)k * EMB * HID, out_acc, 1);
        A = B; B = C;
    }

    // y = relu(out_acc + b_cheb) @ W_out + b_out
    final_kernel<<<(N_NODES * OUTF + 255) / 256, 256, 0, stream>>>(out_acc, bch, Wout, bout, y_out);
}

// Round 11
// 365.271 us; speedup vs baseline: 1.1910x; 1.1410x over previous
//
#include <hip/hip_runtime.h>
#include <hip/hip_fp16.h>

#define N_NODES 50000
#define N_EDGES 1600000
#define F_IN    128
#define EMB     48
#define HID     48
#define OUTF    64
#define KCH     7
#define TPAD    64                   // padded T row length (halves) = 128 B

#define NR    8                      // node ranges (LDS partitions)
#define RANGE (N_NODES / NR)         // 6250 counters
#define BPR   64                     // edge slices
#define SLICE (N_EDGES / BPR)        // 25000 edges per slice (div by 4)
#define HTHREADS 512
#define NBLK  ((N_NODES + 255) / 256)   // 196 reduce blocks
#define XNPB  16                     // nodes per xf block

// ---- pass A: partitioned LDS histogram (cnt by col packed u16, deg by row f32) ----
__global__ __launch_bounds__(HTHREADS) void hist_part_kernel(
    const int* __restrict__ row, const int* __restrict__ col,
    const float* __restrict__ w,
    unsigned short* __restrict__ pc, float* __restrict__ pd)
{
    __shared__ unsigned lc32[RANGE / 2];  // 12.5 KB, 2 u16 counters per word
    __shared__ float    ld[RANGE];        // 25 KB
    int t = threadIdx.x;
    for (int i = t; i < RANGE / 2; i += HTHREADS) lc32[i] = 0u;
    for (int i = t; i < RANGE; i += HTHREADS) ld[i] = 0.f;
    __syncthreads();
    int r = blockIdx.x / BPR;        // node range
    int b = blockIdx.x % BPR;        // edge slice
    int base = r * RANGE;
    int lo = b * SLICE;
    for (int e0 = lo + t * 4; e0 < lo + SLICE; e0 += HTHREADS * 4) {
        int4   c4 = *(const int4*)&col[e0];
        int4   r4 = *(const int4*)&row[e0];
        float4 w4 = *(const float4*)&w[e0];
        int ci, ri;
        ci = c4.x - base; if ((unsigned)ci < RANGE) atomicAdd(&lc32[ci >> 1], 1u << ((ci & 1) * 16));
        ri = r4.x - base; if ((unsigned)ri < RANGE) atomicAdd(&ld[ri], w4.x);
        ci = c4.y - base; if ((unsigned)ci < RANGE) atomicAdd(&lc32[ci >> 1], 1u << ((ci & 1) * 16));
        ri = r4.y - base; if ((unsigned)ri < RANGE) atomicAdd(&ld[ri], w4.y);
        ci = c4.z - base; if ((unsigned)ci < RANGE) atomicAdd(&lc32[ci >> 1], 1u << ((ci & 1) * 16));
        ri = r4.z - base; if ((unsigned)ri < RANGE) atomicAdd(&ld[ri], w4.z);
        ci = c4.w - base; if ((unsigned)ci < RANGE) atomicAdd(&lc32[ci >> 1], 1u << ((ci & 1) * 16));
        ri = r4.w - base; if ((unsigned)ri < RANGE) atomicAdd(&ld[ri], w4.w);
    }
    __syncthreads();
    unsigned short* pcb = pc + (size_t)blockIdx.x * RANGE;
    float*          pdb = pd + (size_t)blockIdx.x * RANGE;
    for (int i = t; i < RANGE; i += HTHREADS) {
        pcb[i] = (unsigned short)((lc32[i >> 1] >> ((i & 1) * 16)) & 0xFFFFu);
        pdb[i] = ld[i];
    }
}

// ---- fold partials: dinv, per-slice prefix (pc in place), AND intra-block
//      exclusive scan of node counts -> off (local), block totals -> bsum ----
__global__ __launch_bounds__(256) void reduce_kernel(
    unsigned short* __restrict__ pc, const float* __restrict__ pd,
    float* __restrict__ dinv, int* __restrict__ off, int* __restrict__ bsum)
{
    int t = threadIdx.x;
    int n = blockIdx.x * 256 + t;
    int c = 0; float d = 0.f;
    if (n < N_NODES) {
        int r = n / RANGE, i = n - r * RANGE;
        size_t base = (size_t)r * BPR * RANGE + i;
        unsigned csum = 0;
        for (int b = 0; b < BPR; ++b) {
            size_t idx = base + (size_t)b * RANGE;
            unsigned x = pc[idx];
            pc[idx] = (unsigned short)csum;
            csum += x;
            d += pd[idx];
        }
        c = (int)csum;
        dinv[n] = d > 0.f ? rsqrtf(d) : 0.f;
    }
    // intra-block exclusive scan of c
    int lane = t & 63, wid = t >> 6;
    int v = c;
    for (int s = 1; s < 64; s <<= 1) {
        int u = __shfl_up(v, s);
        if (lane >= s) v += u;
    }
    __shared__ int ws[4];
    if (lane == 63) ws[wid] = v;
    __syncthreads();
    int wb = 0;
    for (int i = 0; i < 4; ++i) if (i < wid) wb += ws[i];
    int ex = (v - c) + wb;
    if (n < N_NODES) off[n] = ex;
    if (t == 255) bsum[blockIdx.x] = ex + c;
}

// ---- exclusive scan of 196 block sums (tiny, 1 block) ----
__global__ __launch_bounds__(256) void bsum_scan_kernel(
    int* __restrict__ bsum, int* __restrict__ off)
{
    int t = threadIdx.x;
    int orig = (t < NBLK) ? bsum[t] : 0;
    int lane = t & 63, wid = t >> 6;
    int v = orig;
    for (int s = 1; s < 64; s <<= 1) {
        int u = __shfl_up(v, s);
        if (lane >= s) v += u;
    }
    __shared__ int ws[4];
    if (lane == 63) ws[wid] = v;
    __syncthreads();
    int wb = 0;
    for (int i = 0; i < 4; ++i) if (i < wid) wb += ws[i];
    int ex = (v - orig) + wb;
    if (t < NBLK) bsum[t] = ex;
    if (t == NBLK - 1) off[N_NODES] = ex + orig;
}

// ---- add block prefix back: off[n] += bsum[n/256] ----
__global__ __launch_bounds__(256) void add_off_kernel(
    int* __restrict__ off, const int* __restrict__ bsum)
{
    int n = blockIdx.x * 256 + threadIdx.x;
    if (n < N_NODES) off[n] += bsum[n >> 8];
}

// ---- pass D: scatter via re-derived LDS ranks — zero global atomics ----
__global__ __launch_bounds__(HTHREADS) void scatter_part_kernel(
    const int* __restrict__ row, const int* __restrict__ col,
    const float* __restrict__ w, const float* __restrict__ dinv,
    const int* __restrict__ off, const unsigned short* __restrict__ pc,
    uint2* __restrict__ edges)
{
    __shared__ unsigned lc32[RANGE / 2];  // 12.5 KB
    int t = threadIdx.x;
    for (int i = t; i < RANGE / 2; i += HTHREADS) lc32[i] = 0u;
    __syncthreads();
    int r = blockIdx.x / BPR;
    int b = blockIdx.x % BPR;
    int base = r * RANGE;
    int lo = b * SLICE;
    const unsigned short* pcb = pc + (size_t)blockIdx.x * RANGE;
    for (int e0 = lo + t * 4; e0 < lo + SLICE; e0 += HTHREADS * 4) {
        int4   c4 = *(const int4*)&col[e0];
        int4   r4 = *(const int4*)&row[e0];
        float4 w4 = *(const float4*)&w[e0];
        #pragma unroll
        for (int j = 0; j < 4; ++j) {
            int c  = (j == 0) ? c4.x : (j == 1) ? c4.y : (j == 2) ? c4.z : c4.w;
            int rw = (j == 0) ? r4.x : (j == 1) ? r4.y : (j == 2) ? r4.z : r4.w;
            float we = (j == 0) ? w4.x : (j == 1) ? w4.y : (j == 2) ? w4.z : w4.w;
            int ci = c - base;
            if ((unsigned)ci < RANGE) {
                unsigned old = atomicAdd(&lc32[ci >> 1], 1u << ((ci & 1) * 16));
                unsigned lrank = (old >> ((ci & 1) * 16)) & 0xFFFFu;
                float nr = -dinv[rw] * we * dinv[c];
                int pos = off[c] + (int)pcb[ci] + (int)lrank;
                edges[pos] = make_uint2((unsigned)rw, __float_as_uint(nr));
            }
        }
    }
}

// ---- fused xf + k=0 GEMM: xf = relu(x@W_in+b), out_acc = xf@Wch0 ----
// 16 nodes/block; lane owns 4 consecutive outputs (lanes 0-11 active in GEMM):
// per k = 1 broadcast LDS read + 1 ds_read_b128. Writes padded fp16 T0 (pad=0).
__global__ __launch_bounds__(256) void xf_fused_kernel(
    const float* __restrict__ x, const float* __restrict__ Win,
    const float* __restrict__ bin, const float* __restrict__ Wch0,
    float* __restrict__ xf_out, __half* __restrict__ T0h,
    float* __restrict__ out_acc)
{
    __shared__ float Ws[F_IN * EMB];       // 24576 B
    __shared__ float W0s[EMB * HID];       // 9216 B
    __shared__ float xs[XNPB][F_IN + 1];   // 8256 B
    __shared__ float xfS[XNPB][EMB + 1];   // 3136 B
    int t = threadIdx.x;
    for (int i = t; i < F_IN * EMB; i += 256) Ws[i] = Win[i];
    for (int i = t; i < EMB * HID; i += 256) W0s[i] = Wch0[i];
    int n0 = blockIdx.x * XNPB;
    for (int i = t; i < XNPB * (F_IN / 4); i += 256) {
        int ln = i >> 5, k4 = i & 31;     // F_IN/4 == 32
        float4 v = reinterpret_cast<const float4*>(x + (size_t)(n0 + ln) * F_IN)[k4];
        xs[ln][k4 * 4 + 0] = v.x; xs[ln][k4 * 4 + 1] = v.y;
        xs[ln][k4 * 4 + 2] = v.z; xs[ln][k4 * 4 + 3] = v.w;
    }
    __syncthreads();
    int grp = t >> 4, lane = t & 15;
    int g = n0 + grp;
    __half* th = T0h + (size_t)g * TPAD;
    if (lane < 12) {
        float a0 = bin[4 * lane], a1 = bin[4 * lane + 1];
        float a2 = bin[4 * lane + 2], a3 = bin[4 * lane + 3];
#pragma unroll 4
        for (int k = 0; k < F_IN; ++k) {
            float xv = xs[grp][k];
            float4 w4 = *reinterpret_cast<const float4*>(&Ws[k * EMB + 4 * lane]);
            a0 += xv * w4.x; a1 += xv * w4.y; a2 += xv * w4.z; a3 += xv * w4.w;
        }
        a0 = fmaxf(a0, 0.f); a1 = fmaxf(a1, 0.f);
        a2 = fmaxf(a2, 0.f); a3 = fmaxf(a3, 0.f);
        float4 xo4 = make_float4(a0, a1, a2, a3);
        *reinterpret_cast<float4*>(xf_out + (size_t)g * EMB + 4 * lane) = xo4;
        __half2 h01, h23;
        h01.x = __float2half_rn(a0); h01.y = __float2half_rn(a1);
        h23.x = __float2half_rn(a2); h23.y = __float2half_rn(a3);
        uint2 hv;
        hv.x = *reinterpret_cast<unsigned*>(&h01);
        hv.y = *reinterpret_cast<unsigned*>(&h23);
        *reinterpret_cast<uint2*>(th + 4 * lane) = hv;
        xfS[grp][4 * lane]     = a0;
        xfS[grp][4 * lane + 1] = a1;
        xfS[grp][4 * lane + 2] = a2;
        xfS[grp][4 * lane + 3] = a3;
    } else {
        // zero the pad region (features 48..63) — keeps recursion pad-stable
        *reinterpret_cast<uint2*>(th + 4 * lane) = make_uint2(0u, 0u);
    }
    __syncthreads();
    // epilogue: out_acc[g] = xf[g] @ Wch0 ; lane owns {l, l+16, l+32} of HID
    float o0 = 0.f, o1 = 0.f, o2 = 0.f;
#pragma unroll 8
    for (int c = 0; c < EMB; ++c) {
        float tv = xfS[grp][c];
        o0 += tv * W0s[c * HID + lane];
        o1 += tv * W0s[c * HID + lane + 16];
        o2 += tv * W0s[c * HID + lane + 32];
    }
    float* orow = out_acc + (size_t)g * HID;
    orow[lane] = o0; orow[lane + 16] = o1; orow[lane + 32] = o2;
}

// ---- fused: T_k = prop (or 2*prop - tprev) in fp16, out_acc += T_k @ W_k ----
// Padded 128B T rows; lane owns features 4l..4l+3 -> ONE uint2 gather per edge.
__global__ __launch_bounds__(256) void prop_fused_kernel(
    const int* __restrict__ off, const uint2* __restrict__ edges,
    const __half* __restrict__ tsrc, const __half* __restrict__ tprev,
    __half* __restrict__ tdst, const float* __restrict__ Wk,
    float* __restrict__ out_acc, int cheb_mode)
{
    __shared__ float Ws[EMB * HID];     // 9216 B
    __shared__ float tdS[16][TPAD + 1];
    int t = threadIdx.x;
    for (int i = t; i < EMB * HID; i += 256) Ws[i] = Wk[i];

    int grp = t >> 4, lane = t & 15;
    int g = blockIdx.x * 16 + grp;

    float a0 = 0.f, a1 = 0.f, a2 = 0.f, a3 = 0.f;
    int s = off[g], e = off[g + 1];
    int p = s;
    int e8 = s + ((e - s) & ~7);
    for (; p < e8; p += 8) {
        uint2 er[8];
        #pragma unroll
        for (int j = 0; j < 8; ++j) er[j] = edges[p + j];
        float ww[8]; uint2 hv[8];
        #pragma unroll
        for (int j = 0; j < 8; ++j) {
            const __half* tj = tsrc + (size_t)er[j].x * TPAD;
            ww[j] = __uint_as_float(er[j].y);
            hv[j] = *reinterpret_cast<const uint2*>(tj + 4 * lane);
        }
        #pragma unroll
        for (int j = 0; j < 8; ++j) {
            __half2 h01 = *reinterpret_cast<__half2*>(&hv[j].x);
            __half2 h23 = *reinterpret_cast<__half2*>(&hv[j].y);
            a0 += ww[j] * __low2float(h01);
            a1 += ww[j] * __high2float(h01);
            a2 += ww[j] * __low2float(h23);
            a3 += ww[j] * __high2float(h23);
        }
    }
    for (; p < e; ++p) {
        uint2 er = edges[p];
        float wv = __uint_as_float(er.y);
        const __half* tr = tsrc + (size_t)er.x * TPAD;
        uint2 hv = *reinterpret_cast<const uint2*>(tr + 4 * lane);
        __half2 h01 = *reinterpret_cast<__half2*>(&hv.x);
        __half2 h23 = *reinterpret_cast<__half2*>(&hv.y);
        a0 += wv * __low2float(h01);
        a1 += wv * __high2float(h01);
        a2 += wv * __low2float(h23);
        a3 += wv * __high2float(h23);
    }
    if (cheb_mode) {
        uint2 tv = *reinterpret_cast<const uint2*>(tprev + (size_t)g * TPAD + 4 * lane);
        __half2 t01 = *reinterpret_cast<__half2*>(&tv.x);
        __half2 t23 = *reinterpret_cast<__half2*>(&tv.y);
        a0 = 2.f * a0 - __low2float(t01);
        a1 = 2.f * a1 - __high2float(t01);
        a2 = 2.f * a2 - __low2float(t23);
        a3 = 2.f * a3 - __high2float(t23);
    }
    {
        __half2 h01, h23;
        h01.x = __float2half_rn(a0); h01.y = __float2half_rn(a1);
        h23.x = __float2half_rn(a2); h23.y = __float2half_rn(a3);
        uint2 ov;
        ov.x = *reinterpret_cast<unsigned*>(&h01);
        ov.y = *reinterpret_cast<unsigned*>(&h23);
        *reinterpret_cast<uint2*>(tdst + (size_t)g * TPAD + 4 * lane) = ov;
    }
    tdS[grp][4 * lane]     = a0;
    tdS[grp][4 * lane + 1] = a1;
    tdS[grp][4 * lane + 2] = a2;
    tdS[grp][4 * lane + 3] = a3;
    __syncthreads();

    float o0 = 0.f, o1 = 0.f, o2 = 0.f;
#pragma unroll 8
    for (int c = 0; c < EMB; ++c) {
        float tv = tdS[grp][c];
        o0 += tv * Ws[c * HID + lane];
        o1 += tv * Ws[c * HID + lane + 16];
        o2 += tv * Ws[c * HID + lane + 32];
    }
    float* orow = out_acc + (size_t)g * HID;
    orow[lane]      += o0;
    orow[lane + 16] += o1;
    orow[lane + 32] += o2;
}

// ---- y = relu(out_acc + b_cheb) @ W_out + b_out ----
// 16 nodes/block, 16 lanes/node; v staged in LDS per group (same wave, no
// block barrier); lane computes 4 consecutive outputs via float4 W reads.
__global__ __launch_bounds__(256) void final_kernel(
    const float* __restrict__ out_acc, const float* __restrict__ bch,
    const float* __restrict__ Wout, const float* __restrict__ bout,
    float* __restrict__ y)
{
    __shared__ float Ws[HID * OUTF];   // 12288 B
    __shared__ float bs[HID];
    __shared__ float bo[OUTF];
    __shared__ float vS[16][HID + 1];
    int t = threadIdx.x;
    for (int i = t; i < HID * OUTF; i += 256) Ws[i] = Wout[i];
    if (t < HID) bs[t] = bch[t];
    if (t < OUTF) bo[t] = bout[t];
    __syncthreads();
    int grp = t >> 4, lane = t & 15;
    int g = blockIdx.x * 16 + grp;
    const float* orow = out_acc + (size_t)g * HID;
    vS[grp][lane]      = fmaxf(orow[lane]      + bs[lane],      0.f);
    vS[grp][lane + 16] = fmaxf(orow[lane + 16] + bs[lane + 16], 0.f);
    vS[grp][lane + 32] = fmaxf(orow[lane + 32] + bs[lane + 32], 0.f);
    // vS written and read by the same 16 lanes (one wave) — no barrier needed
    float o0 = bo[4 * lane], o1 = bo[4 * lane + 1];
    float o2 = bo[4 * lane + 2], o3 = bo[4 * lane + 3];
#pragma unroll 8
    for (int h = 0; h < HID; ++h) {
        float v = vS[grp][h];
        float4 w4 = *reinterpret_cast<const float4*>(&Ws[h * OUTF + 4 * lane]);
        o0 += v * w4.x; o1 += v * w4.y; o2 += v * w4.z; o3 += v * w4.w;
    }
    *reinterpret_cast<float4*>(y + (size_t)g * OUTF + 4 * lane) =
        make_float4(o0, o1, o2, o3);
}

extern "C" void kernel_launch(void* const* d_in, const int* in_sizes, int n_in,
                              void* d_out, int out_size, void* d_ws, size_t ws_size,
                              hipStream_t stream)
{
    const float* x    = (const float*)d_in[0];
    const int*   ei   = (const int*)d_in[1];
    const float* ew   = (const float*)d_in[2];
    const float* Win  = (const float*)d_in[3];
    const float* bin  = (const float*)d_in[4];
    const float* Wch  = (const float*)d_in[5];   // [7,48,48]
    const float* bch  = (const float*)d_in[6];
    const float* Wout = (const float*)d_in[7];
    const float* bout = (const float*)d_in[8];

    const int* row = ei;
    const int* col = ei + N_EDGES;

    float* y_out  = (float*)d_out;                           // [N,64]
    float* xf_out = (float*)d_out + (size_t)N_NODES * OUTF;  // [N,48]

    // ---- workspace carve (256B aligned); every buffer fully written before read ----
    char* p = (char*)d_ws;
    auto carve = [&](size_t bytes) {
        void* q = p;
        p += (bytes + 255) & ~(size_t)255;
        return q;
    };
    unsigned short* pc = (unsigned short*)carve((size_t)NR * BPR * RANGE * 2); // 6.4 MB
    float*    pd  = (float*)carve((size_t)NR * BPR * RANGE * 4);               // 12.8 MB
    float*    dinv = (float*)carve(N_NODES * 4);
    int*      off  = (int*)  carve((N_NODES + 1) * 4);
    int*      bsum = (int*)  carve(NBLK * 4);
    uint2*    edges = (uint2*)carve((size_t)N_EDGES * 8);
    float*    out_acc = (float*)carve((size_t)N_NODES * HID * 4);
    __half*   T0h = (__half*)carve((size_t)N_NODES * TPAD * 2);   // 6.4 MB each
    __half*   TAh = (__half*)carve((size_t)N_NODES * TPAD * 2);
    __half*   TBh = (__half*)carve((size_t)N_NODES * TPAD * 2);
    __half*   TCh = (__half*)carve((size_t)N_NODES * TPAD * 2);

    // graph preprocessing — zero global atomics, hierarchical scan
    hist_part_kernel<<<NR * BPR, HTHREADS, 0, stream>>>(row, col, ew, pc, pd);
    reduce_kernel<<<NBLK, 256, 0, stream>>>(pc, pd, dinv, off, bsum);
    bsum_scan_kernel<<<1, 256, 0, stream>>>(bsum, off);
    add_off_kernel<<<NBLK, 256, 0, stream>>>(off, bsum);
    scatter_part_kernel<<<NR * BPR, HTHREADS, 0, stream>>>(row, col, ew, dinv, off, pc, edges);

    // xf = relu(x @ W_in + b_in) -> f32 d_out tail + padded fp16 T0, out_acc = xf@Wch0
    xf_fused_kernel<<<N_NODES / XNPB, 256, 0, stream>>>(x, Win, bin, Wch,
                                                        xf_out, T0h, out_acc);

    const int prop_grid = N_NODES / 16;   // 3125, exact

    // T1 = prop(T0); out_acc += T1 @ W1
    prop_fused_kernel<<<prop_grid, 256, 0, stream>>>(off, edges, T0h, nullptr,
                                                     TAh, Wch + EMB * HID, out_acc, 0);
    // Chebyshev recursion with fused GEMM — proven 3-buffer rotation.
    const __half* A = T0h;  // T_{k-2}
    __half*       B = TAh;  // T_{k-1}
    __half* bufs[3] = {TBh, TCh, TAh};
    for (int k = 2; k < KCH; ++k) {
        __half* C = bufs[(k - 2) % 3];
        prop_fused_kernel<<<prop_grid, 256, 0, stream>>>(off, edges, B, A,
                                                         C, Wch + (size_t)k * EMB * HID, out_acc, 1);
        A = B; B = C;
    }

    // y = relu(out_acc + b_cheb) @ W_out + b_out
    final_kernel<<<N_NODES / 16, 256, 0, stream>>>(out_acc, bch, Wout, bout, y_out);
}

// Round 12
// 361.077 us; speedup vs baseline: 1.2048x; 1.0116x over previous
//
#include <hip/hip_runtime.h>
#include <hip/hip_fp16.h>

#define N_NODES 50000
#define N_EDGES 1600000
#define F_IN    128
#define EMB     48
#define HID     48
#define OUTF    64
#define KCH     7
#define TPAD    64                   // padded T row length (halves) = 128 B

#define NR    8                      // node ranges (LDS partitions)
#define RANGE (N_NODES / NR)         // 6250 counters
#define BPR   64                     // edge slices
#define SLICE (N_EDGES / BPR)        // 25000 edges per slice (div by 4)
#define HTHREADS 512
#define NBLK  ((N_NODES + 255) / 256)   // 196 reduce blocks

// ---- pass A: partitioned LDS histogram (cnt by col packed u16, deg by row f32) ----
__global__ __launch_bounds__(HTHREADS) void hist_part_kernel(
    const int* __restrict__ row, const int* __restrict__ col,
    const float* __restrict__ w,
    unsigned short* __restrict__ pc, float* __restrict__ pd)
{
    __shared__ unsigned lc32[RANGE / 2];  // 12.5 KB, 2 u16 counters per word
    __shared__ float    ld[RANGE];        // 25 KB
    int t = threadIdx.x;
    for (int i = t; i < RANGE / 2; i += HTHREADS) lc32[i] = 0u;
    for (int i = t; i < RANGE; i += HTHREADS) ld[i] = 0.f;
    __syncthreads();
    int r = blockIdx.x / BPR;        // node range
    int b = blockIdx.x % BPR;        // edge slice
    int base = r * RANGE;
    int lo = b * SLICE;
    for (int e0 = lo + t * 4; e0 < lo + SLICE; e0 += HTHREADS * 4) {
        int4   c4 = *(const int4*)&col[e0];
        int4   r4 = *(const int4*)&row[e0];
        float4 w4 = *(const float4*)&w[e0];
        int ci, ri;
        ci = c4.x - base; if ((unsigned)ci < RANGE) atomicAdd(&lc32[ci >> 1], 1u << ((ci & 1) * 16));
        ri = r4.x - base; if ((unsigned)ri < RANGE) atomicAdd(&ld[ri], w4.x);
        ci = c4.y - base; if ((unsigned)ci < RANGE) atomicAdd(&lc32[ci >> 1], 1u << ((ci & 1) * 16));
        ri = r4.y - base; if ((unsigned)ri < RANGE) atomicAdd(&ld[ri], w4.y);
        ci = c4.z - base; if ((unsigned)ci < RANGE) atomicAdd(&lc32[ci >> 1], 1u << ((ci & 1) * 16));
        ri = r4.z - base; if ((unsigned)ri < RANGE) atomicAdd(&ld[ri], w4.z);
        ci = c4.w - base; if ((unsigned)ci < RANGE) atomicAdd(&lc32[ci >> 1], 1u << ((ci & 1) * 16));
        ri = r4.w - base; if ((unsigned)ri < RANGE) atomicAdd(&ld[ri], w4.w);
    }
    __syncthreads();
    unsigned short* pcb = pc + (size_t)blockIdx.x * RANGE;
    float*          pdb = pd + (size_t)blockIdx.x * RANGE;
    for (int i = t; i < RANGE; i += HTHREADS) {
        pcb[i] = (unsigned short)((lc32[i >> 1] >> ((i & 1) * 16)) & 0xFFFFu);
        pdb[i] = ld[i];
    }
}

// ---- fold partials: dinv, per-slice prefix (pc in place), AND intra-block
//      exclusive scan of node counts -> off (local), block totals -> bsum ----
__global__ __launch_bounds__(256) void reduce_kernel(
    unsigned short* __restrict__ pc, const float* __restrict__ pd,
    float* __restrict__ dinv, int* __restrict__ off, int* __restrict__ bsum)
{
    int t = threadIdx.x;
    int n = blockIdx.x * 256 + t;
    int c = 0; float d = 0.f;
    if (n < N_NODES) {
        int r = n / RANGE, i = n - r * RANGE;
        size_t base = (size_t)r * BPR * RANGE + i;
        unsigned csum = 0;
        for (int b = 0; b < BPR; ++b) {
            size_t idx = base + (size_t)b * RANGE;
            unsigned x = pc[idx];
            pc[idx] = (unsigned short)csum;
            csum += x;
            d += pd[idx];
        }
        c = (int)csum;
        dinv[n] = d > 0.f ? rsqrtf(d) : 0.f;
    }
    // intra-block exclusive scan of c
    int lane = t & 63, wid = t >> 6;
    int v = c;
    for (int s = 1; s < 64; s <<= 1) {
        int u = __shfl_up(v, s);
        if (lane >= s) v += u;
    }
    __shared__ int ws[4];
    if (lane == 63) ws[wid] = v;
    __syncthreads();
    int wb = 0;
    for (int i = 0; i < 4; ++i) if (i < wid) wb += ws[i];
    int ex = (v - c) + wb;
    if (n < N_NODES) off[n] = ex;
    if (t == 255) bsum[blockIdx.x] = ex + c;
}

// ---- exclusive scan of 196 block sums (tiny, 1 block) ----
__global__ __launch_bounds__(256) void bsum_scan_kernel(
    int* __restrict__ bsum, int* __restrict__ off)
{
    int t = threadIdx.x;
    int orig = (t < NBLK) ? bsum[t] : 0;
    int lane = t & 63, wid = t >> 6;
    int v = orig;
    for (int s = 1; s < 64; s <<= 1) {
        int u = __shfl_up(v, s);
        if (lane >= s) v += u;
    }
    __shared__ int ws[4];
    if (lane == 63) ws[wid] = v;
    __syncthreads();
    int wb = 0;
    for (int i = 0; i < 4; ++i) if (i < wid) wb += ws[i];
    int ex = (v - orig) + wb;
    if (t < NBLK) bsum[t] = ex;
    if (t == NBLK - 1) off[N_NODES] = ex + orig;
}

// ---- add block prefix back: off[n] += bsum[n/256] ----
__global__ __launch_bounds__(256) void add_off_kernel(
    int* __restrict__ off, const int* __restrict__ bsum)
{
    int n = blockIdx.x * 256 + threadIdx.x;
    if (n < N_NODES) off[n] += bsum[n >> 8];
}

// ---- pass D: scatter via re-derived LDS ranks — zero global atomics ----
__global__ __launch_bounds__(HTHREADS) void scatter_part_kernel(
    const int* __restrict__ row, const int* __restrict__ col,
    const float* __restrict__ w, const float* __restrict__ dinv,
    const int* __restrict__ off, const unsigned short* __restrict__ pc,
    uint2* __restrict__ edges)
{
    __shared__ unsigned lc32[RANGE / 2];  // 12.5 KB
    int t = threadIdx.x;
    for (int i = t; i < RANGE / 2; i += HTHREADS) lc32[i] = 0u;
    __syncthreads();
    int r = blockIdx.x / BPR;
    int b = blockIdx.x % BPR;
    int base = r * RANGE;
    int lo = b * SLICE;
    const unsigned short* pcb = pc + (size_t)blockIdx.x * RANGE;
    for (int e0 = lo + t * 4; e0 < lo + SLICE; e0 += HTHREADS * 4) {
        int4   c4 = *(const int4*)&col[e0];
        int4   r4 = *(const int4*)&row[e0];
        float4 w4 = *(const float4*)&w[e0];
        #pragma unroll
        for (int j = 0; j < 4; ++j) {
            int c  = (j == 0) ? c4.x : (j == 1) ? c4.y : (j == 2) ? c4.z : c4.w;
            int rw = (j == 0) ? r4.x : (j == 1) ? r4.y : (j == 2) ? r4.z : r4.w;
            float we = (j == 0) ? w4.x : (j == 1) ? w4.y : (j == 2) ? w4.z : w4.w;
            int ci = c - base;
            if ((unsigned)ci < RANGE) {
                unsigned old = atomicAdd(&lc32[ci >> 1], 1u << ((ci & 1) * 16));
                unsigned lrank = (old >> ((ci & 1) * 16)) & 0xFFFFu;
                float nr = -dinv[rw] * we * dinv[c];
                int pos = off[c] + (int)pcb[ci] + (int)lrank;
                edges[pos] = make_uint2((unsigned)rw, __float_as_uint(nr));
            }
        }
    }
}

// ---- fused xf + k=0 GEMM, thread-per-node ----
// 48 f32 accumulators in VGPRs; per k: 1 float4 x read + broadcast LDS W reads
// + 48 independent FMAs. Epilogue out_acc = xf@Wch0 also in-register.
__global__ __launch_bounds__(128) void xf_fused_kernel(
    const float* __restrict__ x, const float* __restrict__ Win,
    const float* __restrict__ bin, const float* __restrict__ Wch0,
    float* __restrict__ xf_out, __half* __restrict__ T0h,
    float* __restrict__ out_acc)
{
    __shared__ float Ws[F_IN * EMB];       // 24576 B
    __shared__ float W0s[EMB * HID];       // 9216 B
    __shared__ float bs[EMB];
    int t = threadIdx.x;
    for (int i = t; i < F_IN * EMB; i += 128) Ws[i] = Win[i];
    for (int i = t; i < EMB * HID; i += 128) W0s[i] = Wch0[i];
    if (t < EMB) bs[t] = bin[t];
    __syncthreads();
    int n = blockIdx.x * 128 + t;
    if (n >= N_NODES) return;

    float acc[EMB];
#pragma unroll
    for (int c = 0; c < EMB; ++c) acc[c] = bs[c];
    const float4* xr = reinterpret_cast<const float4*>(x + (size_t)n * F_IN);
#pragma unroll 2
    for (int k4 = 0; k4 < F_IN / 4; ++k4) {
        float4 xv = xr[k4];
#pragma unroll
        for (int j = 0; j < 4; ++j) {
            float xvf = (j == 0) ? xv.x : (j == 1) ? xv.y : (j == 2) ? xv.z : xv.w;
            const float* wk = &Ws[(k4 * 4 + j) * EMB];
#pragma unroll
            for (int c = 0; c < EMB; ++c) acc[c] += xvf * wk[c];
        }
    }
#pragma unroll
    for (int c = 0; c < EMB; ++c) acc[c] = fmaxf(acc[c], 0.f);

    // write xf (f32, output 1)
    float* xo = xf_out + (size_t)n * EMB;
#pragma unroll
    for (int c4 = 0; c4 < EMB / 4; ++c4)
        reinterpret_cast<float4*>(xo)[c4] =
            make_float4(acc[4 * c4], acc[4 * c4 + 1], acc[4 * c4 + 2], acc[4 * c4 + 3]);

    // write padded fp16 T0 (pad region zero)
    __half* th = T0h + (size_t)n * TPAD;
#pragma unroll
    for (int c8 = 0; c8 < EMB / 8; ++c8) {
        uint4 hv; __half2 h;
        h.x = __float2half_rn(acc[8 * c8 + 0]); h.y = __float2half_rn(acc[8 * c8 + 1]);
        hv.x = *reinterpret_cast<unsigned*>(&h);
        h.x = __float2half_rn(acc[8 * c8 + 2]); h.y = __float2half_rn(acc[8 * c8 + 3]);
        hv.y = *reinterpret_cast<unsigned*>(&h);
        h.x = __float2half_rn(acc[8 * c8 + 4]); h.y = __float2half_rn(acc[8 * c8 + 5]);
        hv.z = *reinterpret_cast<unsigned*>(&h);
        h.x = __float2half_rn(acc[8 * c8 + 6]); h.y = __float2half_rn(acc[8 * c8 + 7]);
        hv.w = *reinterpret_cast<unsigned*>(&h);
        reinterpret_cast<uint4*>(th)[c8] = hv;
    }
    reinterpret_cast<uint4*>(th)[6] = make_uint4(0, 0, 0, 0);
    reinterpret_cast<uint4*>(th)[7] = make_uint4(0, 0, 0, 0);

    // out_acc = xf @ Wch0
    float outv[HID];
#pragma unroll
    for (int h = 0; h < HID; ++h) outv[h] = 0.f;
    for (int c = 0; c < EMB; ++c) {
        float a = acc[c];
        const float* w0 = &W0s[c * HID];
#pragma unroll
        for (int h = 0; h < HID; ++h) outv[h] += a * w0[h];
    }
    float* orow = out_acc + (size_t)n * HID;
#pragma unroll
    for (int h4 = 0; h4 < HID / 4; ++h4)
        reinterpret_cast<float4*>(orow)[h4] =
            make_float4(outv[4 * h4], outv[4 * h4 + 1], outv[4 * h4 + 2], outv[4 * h4 + 3]);
}

// ---- fused: T_k = prop (or 2*prop - tprev) in fp16, out_acc += T_k @ W_k ----
// Padded 128B T rows; lane owns features 4l..4l+3 -> ONE uint2 gather per edge.
__global__ __launch_bounds__(256) void prop_fused_kernel(
    const int* __restrict__ off, const uint2* __restrict__ edges,
    const __half* __restrict__ tsrc, const __half* __restrict__ tprev,
    __half* __restrict__ tdst, const float* __restrict__ Wk,
    float* __restrict__ out_acc, int cheb_mode)
{
    __shared__ float Ws[EMB * HID];     // 9216 B
    __shared__ float tdS[16][TPAD + 1];
    int t = threadIdx.x;
    for (int i = t; i < EMB * HID; i += 256) Ws[i] = Wk[i];

    int grp = t >> 4, lane = t & 15;
    int g = blockIdx.x * 16 + grp;

    float a0 = 0.f, a1 = 0.f, a2 = 0.f, a3 = 0.f;
    int s = off[g], e = off[g + 1];
    int p = s;
    int e8 = s + ((e - s) & ~7);
    for (; p < e8; p += 8) {
        uint2 er[8];
        #pragma unroll
        for (int j = 0; j < 8; ++j) er[j] = edges[p + j];
        float ww[8]; uint2 hv[8];
        #pragma unroll
        for (int j = 0; j < 8; ++j) {
            const __half* tj = tsrc + (size_t)er[j].x * TPAD;
            ww[j] = __uint_as_float(er[j].y);
            hv[j] = *reinterpret_cast<const uint2*>(tj + 4 * lane);
        }
        #pragma unroll
        for (int j = 0; j < 8; ++j) {
            __half2 h01 = *reinterpret_cast<__half2*>(&hv[j].x);
            __half2 h23 = *reinterpret_cast<__half2*>(&hv[j].y);
            a0 += ww[j] * __low2float(h01);
            a1 += ww[j] * __high2float(h01);
            a2 += ww[j] * __low2float(h23);
            a3 += ww[j] * __high2float(h23);
        }
    }
    for (; p < e; ++p) {
        uint2 er = edges[p];
        float wv = __uint_as_float(er.y);
        const __half* tr = tsrc + (size_t)er.x * TPAD;
        uint2 hv = *reinterpret_cast<const uint2*>(tr + 4 * lane);
        __half2 h01 = *reinterpret_cast<__half2*>(&hv.x);
        __half2 h23 = *reinterpret_cast<__half2*>(&hv.y);
        a0 += wv * __low2float(h01);
        a1 += wv * __high2float(h01);
        a2 += wv * __low2float(h23);
        a3 += wv * __high2float(h23);
    }
    if (cheb_mode) {
        uint2 tv = *reinterpret_cast<const uint2*>(tprev + (size_t)g * TPAD + 4 * lane);
        __half2 t01 = *reinterpret_cast<__half2*>(&tv.x);
        __half2 t23 = *reinterpret_cast<__half2*>(&tv.y);
        a0 = 2.f * a0 - __low2float(t01);
        a1 = 2.f * a1 - __high2float(t01);
        a2 = 2.f * a2 - __low2float(t23);
        a3 = 2.f * a3 - __high2float(t23);
    }
    {
        __half2 h01, h23;
        h01.x = __float2half_rn(a0); h01.y = __float2half_rn(a1);
        h23.x = __float2half_rn(a2); h23.y = __float2half_rn(a3);
        uint2 ov;
        ov.x = *reinterpret_cast<unsigned*>(&h01);
        ov.y = *reinterpret_cast<unsigned*>(&h23);
        *reinterpret_cast<uint2*>(tdst + (size_t)g * TPAD + 4 * lane) = ov;
    }
    tdS[grp][4 * lane]     = a0;
    tdS[grp][4 * lane + 1] = a1;
    tdS[grp][4 * lane + 2] = a2;
    tdS[grp][4 * lane + 3] = a3;
    __syncthreads();

    float o0 = 0.f, o1 = 0.f, o2 = 0.f;
#pragma unroll 8
    for (int c = 0; c < EMB; ++c) {
        float tv = tdS[grp][c];
        o0 += tv * Ws[c * HID + lane];
        o1 += tv * Ws[c * HID + lane + 16];
        o2 += tv * Ws[c * HID + lane + 32];
    }
    float* orow = out_acc + (size_t)g * HID;
    orow[lane]      += o0;
    orow[lane + 16] += o1;
    orow[lane + 32] += o2;
}

// ---- LAST prop (k=6) fused with final: no T write, no out_acc writeback;
// y = relu(out_acc + T6@W6 + b_cheb) @ W_out + b_out ----
__global__ __launch_bounds__(256) void prop_final_kernel(
    const int* __restrict__ off, const uint2* __restrict__ edges,
    const __half* __restrict__ tsrc, const __half* __restrict__ tprev,
    const float* __restrict__ Wk, const float* __restrict__ out_acc,
    const float* __restrict__ bch, const float* __restrict__ Wout,
    const float* __restrict__ bout, float* __restrict__ y)
{
    __shared__ float Ws[EMB * HID];      // 9216 B
    __shared__ float Wo[HID * OUTF];     // 12288 B
    __shared__ float tdS[16][TPAD + 1];  // 4160 B
    __shared__ float vS[16][HID + 1];    // 3136 B
    __shared__ float bchS[HID];
    __shared__ float boS[OUTF];
    int t = threadIdx.x;
    for (int i = t; i < EMB * HID; i += 256) Ws[i] = Wk[i];
    for (int i = t; i < HID * OUTF; i += 256) Wo[i] = Wout[i];
    if (t < HID) bchS[t] = bch[t];
    if (t < OUTF) boS[t] = bout[t];

    int grp = t >> 4, lane = t & 15;
    int g = blockIdx.x * 16 + grp;

    float a0 = 0.f, a1 = 0.f, a2 = 0.f, a3 = 0.f;
    int s = off[g], e = off[g + 1];
    int p = s;
    int e8 = s + ((e - s) & ~7);
    for (; p < e8; p += 8) {
        uint2 er[8];
        #pragma unroll
        for (int j = 0; j < 8; ++j) er[j] = edges[p + j];
        float ww[8]; uint2 hv[8];
        #pragma unroll
        for (int j = 0; j < 8; ++j) {
            const __half* tj = tsrc + (size_t)er[j].x * TPAD;
            ww[j] = __uint_as_float(er[j].y);
            hv[j] = *reinterpret_cast<const uint2*>(tj + 4 * lane);
        }
        #pragma unroll
        for (int j = 0; j < 8; ++j) {
            __half2 h01 = *reinterpret_cast<__half2*>(&hv[j].x);
            __half2 h23 = *reinterpret_cast<__half2*>(&hv[j].y);
            a0 += ww[j] * __low2float(h01);
            a1 += ww[j] * __high2float(h01);
            a2 += ww[j] * __low2float(h23);
            a3 += ww[j] * __high2float(h23);
        }
    }
    for (; p < e; ++p) {
        uint2 er = edges[p];
        float wv = __uint_as_float(er.y);
        const __half* tr = tsrc + (size_t)er.x * TPAD;
        uint2 hv = *reinterpret_cast<const uint2*>(tr + 4 * lane);
        __half2 h01 = *reinterpret_cast<__half2*>(&hv.x);
        __half2 h23 = *reinterpret_cast<__half2*>(&hv.y);
        a0 += wv * __low2float(h01);
        a1 += wv * __high2float(h01);
        a2 += wv * __low2float(h23);
        a3 += wv * __high2float(h23);
    }
    {
        uint2 tv = *reinterpret_cast<const uint2*>(tprev + (size_t)g * TPAD + 4 * lane);
        __half2 t01 = *reinterpret_cast<__half2*>(&tv.x);
        __half2 t23 = *reinterpret_cast<__half2*>(&tv.y);
        a0 = 2.f * a0 - __low2float(t01);
        a1 = 2.f * a1 - __high2float(t01);
        a2 = 2.f * a2 - __low2float(t23);
        a3 = 2.f * a3 - __high2float(t23);
    }
    tdS[grp][4 * lane]     = a0;
    tdS[grp][4 * lane + 1] = a1;
    tdS[grp][4 * lane + 2] = a2;
    tdS[grp][4 * lane + 3] = a3;
    __syncthreads();

    // epilogue 1: v = relu(out_acc + T6@W6 + bch)  (same-wave group, no barrier)
    float o0 = 0.f, o1 = 0.f, o2 = 0.f;
#pragma unroll 8
    for (int c = 0; c < EMB; ++c) {
        float tv = tdS[grp][c];
        o0 += tv * Ws[c * HID + lane];
        o1 += tv * Ws[c * HID + lane + 16];
        o2 += tv * Ws[c * HID + lane + 32];
    }
    const float* orow = out_acc + (size_t)g * HID;
    vS[grp][lane]      = fmaxf(orow[lane]      + o0 + bchS[lane],      0.f);
    vS[grp][lane + 16] = fmaxf(orow[lane + 16] + o1 + bchS[lane + 16], 0.f);
    vS[grp][lane + 32] = fmaxf(orow[lane + 32] + o2 + bchS[lane + 32], 0.f);

    // epilogue 2: y[g][4l..4l+3] = v @ W_out + b_out
    float y0 = boS[4 * lane], y1 = boS[4 * lane + 1];
    float y2 = boS[4 * lane + 2], y3 = boS[4 * lane + 3];
#pragma unroll 8
    for (int h = 0; h < HID; ++h) {
        float v = vS[grp][h];
        float4 w4 = *reinterpret_cast<const float4*>(&Wo[h * OUTF + 4 * lane]);
        y0 += v * w4.x; y1 += v * w4.y; y2 += v * w4.z; y3 += v * w4.w;
    }
    *reinterpret_cast<float4*>(y + (size_t)g * OUTF + 4 * lane) =
        make_float4(y0, y1, y2, y3);
}

extern "C" void kernel_launch(void* const* d_in, const int* in_sizes, int n_in,
                              void* d_out, int out_size, void* d_ws, size_t ws_size,
                              hipStream_t stream)
{
    const float* x    = (const float*)d_in[0];
    const int*   ei   = (const int*)d_in[1];
    const float* ew   = (const float*)d_in[2];
    const float* Win  = (const float*)d_in[3];
    const float* bin  = (const float*)d_in[4];
    const float* Wch  = (const float*)d_in[5];   // [7,48,48]
    const float* bch  = (const float*)d_in[6];
    const float* Wout = (const float*)d_in[7];
    const float* bout = (const float*)d_in[8];

    const int* row = ei;
    const int* col = ei + N_EDGES;

    float* y_out  = (float*)d_out;                           // [N,64]
    float* xf_out = (float*)d_out + (size_t)N_NODES * OUTF;  // [N,48]

    // ---- workspace carve (256B aligned); every buffer fully written before read ----
    char* p = (char*)d_ws;
    auto carve = [&](size_t bytes) {
        void* q = p;
        p += (bytes + 255) & ~(size_t)255;
        return q;
    };
    unsigned short* pc = (unsigned short*)carve((size_t)NR * BPR * RANGE * 2); // 6.4 MB
    float*    pd  = (float*)carve((size_t)NR * BPR * RANGE * 4);               // 12.8 MB
    float*    dinv = (float*)carve(N_NODES * 4);
    int*      off  = (int*)  carve((N_NODES + 1) * 4);
    int*      bsum = (int*)  carve(NBLK * 4);
    uint2*    edges = (uint2*)carve((size_t)N_EDGES * 8);
    float*    out_acc = (float*)carve((size_t)N_NODES * HID * 4);
    __half*   T0h = (__half*)carve((size_t)N_NODES * TPAD * 2);   // 6.4 MB each
    __half*   TAh = (__half*)carve((size_t)N_NODES * TPAD * 2);
    __half*   TBh = (__half*)carve((size_t)N_NODES * TPAD * 2);
    __half*   TCh = (__half*)carve((size_t)N_NODES * TPAD * 2);

    // graph preprocessing — zero global atomics, hierarchical scan
    hist_part_kernel<<<NR * BPR, HTHREADS, 0, stream>>>(row, col, ew, pc, pd);
    reduce_kernel<<<NBLK, 256, 0, stream>>>(pc, pd, dinv, off, bsum);
    bsum_scan_kernel<<<1, 256, 0, stream>>>(bsum, off);
    add_off_kernel<<<NBLK, 256, 0, stream>>>(off, bsum);
    scatter_part_kernel<<<NR * BPR, HTHREADS, 0, stream>>>(row, col, ew, dinv, off, pc, edges);

    // xf = relu(x @ W_in + b_in) -> f32 d_out tail + padded fp16 T0, out_acc = xf@Wch0
    xf_fused_kernel<<<(N_NODES + 127) / 128, 128, 0, stream>>>(x, Win, bin, Wch,
                                                               xf_out, T0h, out_acc);

    const int prop_grid = N_NODES / 16;   // 3125, exact

    // T1 = prop(T0); out_acc += T1 @ W1
    prop_fused_kernel<<<prop_grid, 256, 0, stream>>>(off, edges, T0h, nullptr,
                                                     TAh, Wch + EMB * HID, out_acc, 0);
    // Chebyshev recursion k=2..5 with fused GEMM — proven 3-buffer rotation.
    const __half* A = T0h;  // T_{k-2}
    __half*       B = TAh;  // T_{k-1}
    __half* bufs[3] = {TBh, TCh, TAh};
    for (int k = 2; k < KCH - 1; ++k) {
        __half* C = bufs[(k - 2) % 3];
        prop_fused_kernel<<<prop_grid, 256, 0, stream>>>(off, edges, B, A,
                                                         C, Wch + (size_t)k * EMB * HID, out_acc, 1);
        A = B; B = C;
    }
    // k=6: fused prop + final (no T6 write, no out_acc writeback)
    prop_final_kernel<<<prop_grid, 256, 0, stream>>>(off, edges, B, A,
                                                     Wch + (size_t)(KCH - 1) * EMB * HID,
                                                     out_acc, bch, Wout, bout, y_out);
}

// Round 13
// 351.111 us; speedup vs baseline: 1.2390x; 1.0284x over previous
//
#include <hip/hip_runtime.h>
#include <hip/hip_fp16.h>

#define N_NODES 50000
#define N_EDGES 1600000
#define F_IN    128
#define EMB     48
#define HID     48
#define OUTF    64
#define KCH     7
#define TPAD    64                   // padded T row length (halves) = 128 B

#define NR    8                      // node ranges (LDS partitions)
#define RANGE (N_NODES / NR)         // 6250 counters
#define BPR   64                     // edge slices
#define SLICE (N_EDGES / BPR)        // 25000 edges per slice (div by 4)
#define HTHREADS 512
#define NBLK  ((N_NODES + 255) / 256)   // 196 reduce blocks
#define NTILES (N_NODES / 16)        // 3125 node tiles

typedef __attribute__((ext_vector_type(8))) _Float16 half8;
typedef __attribute__((ext_vector_type(4))) float f32x4;

// ---- pass A: partitioned LDS histogram (cnt by col packed u16, deg by row f32) ----
__global__ __launch_bounds__(HTHREADS) void hist_part_kernel(
    const int* __restrict__ row, const int* __restrict__ col,
    const float* __restrict__ w,
    unsigned short* __restrict__ pc, float* __restrict__ pd)
{
    __shared__ unsigned lc32[RANGE / 2];  // 12.5 KB, 2 u16 counters per word
    __shared__ float    ld[RANGE];        // 25 KB
    int t = threadIdx.x;
    for (int i = t; i < RANGE / 2; i += HTHREADS) lc32[i] = 0u;
    for (int i = t; i < RANGE; i += HTHREADS) ld[i] = 0.f;
    __syncthreads();
    int r = blockIdx.x / BPR;        // node range
    int b = blockIdx.x % BPR;        // edge slice
    int base = r * RANGE;
    int lo = b * SLICE;
    for (int e0 = lo + t * 4; e0 < lo + SLICE; e0 += HTHREADS * 4) {
        int4   c4 = *(const int4*)&col[e0];
        int4   r4 = *(const int4*)&row[e0];
        float4 w4 = *(const float4*)&w[e0];
        int ci, ri;
        ci = c4.x - base; if ((unsigned)ci < RANGE) atomicAdd(&lc32[ci >> 1], 1u << ((ci & 1) * 16));
        ri = r4.x - base; if ((unsigned)ri < RANGE) atomicAdd(&ld[ri], w4.x);
        ci = c4.y - base; if ((unsigned)ci < RANGE) atomicAdd(&lc32[ci >> 1], 1u << ((ci & 1) * 16));
        ri = r4.y - base; if ((unsigned)ri < RANGE) atomicAdd(&ld[ri], w4.y);
        ci = c4.z - base; if ((unsigned)ci < RANGE) atomicAdd(&lc32[ci >> 1], 1u << ((ci & 1) * 16));
        ri = r4.z - base; if ((unsigned)ri < RANGE) atomicAdd(&ld[ri], w4.z);
        ci = c4.w - base; if ((unsigned)ci < RANGE) atomicAdd(&lc32[ci >> 1], 1u << ((ci & 1) * 16));
        ri = r4.w - base; if ((unsigned)ri < RANGE) atomicAdd(&ld[ri], w4.w);
    }
    __syncthreads();
    unsigned short* pcb = pc + (size_t)blockIdx.x * RANGE;
    float*          pdb = pd + (size_t)blockIdx.x * RANGE;
    for (int i = t; i < RANGE; i += HTHREADS) {
        pcb[i] = (unsigned short)((lc32[i >> 1] >> ((i & 1) * 16)) & 0xFFFFu);
        pdb[i] = ld[i];
    }
}

// ---- fold partials: dinv, per-slice prefix (pc in place), intra-block scan ----
__global__ __launch_bounds__(256) void reduce_kernel(
    unsigned short* __restrict__ pc, const float* __restrict__ pd,
    float* __restrict__ dinv, int* __restrict__ off, int* __restrict__ bsum)
{
    int t = threadIdx.x;
    int n = blockIdx.x * 256 + t;
    int c = 0; float d = 0.f;
    if (n < N_NODES) {
        int r = n / RANGE, i = n - r * RANGE;
        size_t base = (size_t)r * BPR * RANGE + i;
        unsigned csum = 0;
        for (int b = 0; b < BPR; ++b) {
            size_t idx = base + (size_t)b * RANGE;
            unsigned x = pc[idx];
            pc[idx] = (unsigned short)csum;
            csum += x;
            d += pd[idx];
        }
        c = (int)csum;
        dinv[n] = d > 0.f ? rsqrtf(d) : 0.f;
    }
    int lane = t & 63, wid = t >> 6;
    int v = c;
    for (int s = 1; s < 64; s <<= 1) {
        int u = __shfl_up(v, s);
        if (lane >= s) v += u;
    }
    __shared__ int ws[4];
    if (lane == 63) ws[wid] = v;
    __syncthreads();
    int wb = 0;
    for (int i = 0; i < 4; ++i) if (i < wid) wb += ws[i];
    int ex = (v - c) + wb;
    if (n < N_NODES) off[n] = ex;
    if (t == 255) bsum[blockIdx.x] = ex + c;
}

// ---- exclusive scan of 196 block sums ----
__global__ __launch_bounds__(256) void bsum_scan_kernel(
    int* __restrict__ bsum, int* __restrict__ off)
{
    int t = threadIdx.x;
    int orig = (t < NBLK) ? bsum[t] : 0;
    int lane = t & 63, wid = t >> 6;
    int v = orig;
    for (int s = 1; s < 64; s <<= 1) {
        int u = __shfl_up(v, s);
        if (lane >= s) v += u;
    }
    __shared__ int ws[4];
    if (lane == 63) ws[wid] = v;
    __syncthreads();
    int wb = 0;
    for (int i = 0; i < 4; ++i) if (i < wid) wb += ws[i];
    int ex = (v - orig) + wb;
    if (t < NBLK) bsum[t] = ex;
    if (t == NBLK - 1) off[N_NODES] = ex + orig;
}

// ---- add block prefix back ----
__global__ __launch_bounds__(256) void add_off_kernel(
    int* __restrict__ off, const int* __restrict__ bsum)
{
    int n = blockIdx.x * 256 + threadIdx.x;
    if (n < N_NODES) off[n] += bsum[n >> 8];
}

// ---- pass D: scatter via re-derived LDS ranks — zero global atomics ----
__global__ __launch_bounds__(HTHREADS) void scatter_part_kernel(
    const int* __restrict__ row, const int* __restrict__ col,
    const float* __restrict__ w, const float* __restrict__ dinv,
    const int* __restrict__ off, const unsigned short* __restrict__ pc,
    uint2* __restrict__ edges)
{
    __shared__ unsigned lc32[RANGE / 2];  // 12.5 KB
    int t = threadIdx.x;
    for (int i = t; i < RANGE / 2; i += HTHREADS) lc32[i] = 0u;
    __syncthreads();
    int r = blockIdx.x / BPR;
    int b = blockIdx.x % BPR;
    int base = r * RANGE;
    int lo = b * SLICE;
    const unsigned short* pcb = pc + (size_t)blockIdx.x * RANGE;
    for (int e0 = lo + t * 4; e0 < lo + SLICE; e0 += HTHREADS * 4) {
        int4   c4 = *(const int4*)&col[e0];
        int4   r4 = *(const int4*)&row[e0];
        float4 w4 = *(const float4*)&w[e0];
        #pragma unroll
        for (int j = 0; j < 4; ++j) {
            int c  = (j == 0) ? c4.x : (j == 1) ? c4.y : (j == 2) ? c4.z : c4.w;
            int rw = (j == 0) ? r4.x : (j == 1) ? r4.y : (j == 2) ? r4.z : r4.w;
            float we = (j == 0) ? w4.x : (j == 1) ? w4.y : (j == 2) ? w4.z : w4.w;
            int ci = c - base;
            if ((unsigned)ci < RANGE) {
                unsigned old = atomicAdd(&lc32[ci >> 1], 1u << ((ci & 1) * 16));
                unsigned lrank = (old >> ((ci & 1) * 16)) & 0xFFFFu;
                float nr = -dinv[rw] * we * dinv[c];
                int pos = off[c] + (int)pcb[ci] + (int)lrank;
                edges[pos] = make_uint2((unsigned)rw, __float_as_uint(nr));
            }
        }
    }
}

// ---- MFMA xf: xf = relu(x @ W_in + b_in), one wave per 16-node tile ----
// A-frag: lane holds x[n0 + (lane&15)][k = (lane>>4)*8 .. +8] (8 k-contig, f16).
// B-frags pre-packed in LDS. C/D: col = lane&15, row = (lane>>4)*4 + reg.
__global__ __launch_bounds__(256) void xf_mfma_kernel(
    const float* __restrict__ x, const float* __restrict__ Win,
    const float* __restrict__ bin, float* __restrict__ xf_out,
    __half* __restrict__ T0h)
{
    __shared__ half8 Wf[3][4][64];   // 12288 B
    __shared__ float bs[EMB];
    int t = threadIdx.x;
    // stage W fragments: entry (j, s, l) -> W[s*32 + (l>>4)*8 + i][j*16 + (l&15)]
    for (int idx = t; idx < 3 * 4 * 64; idx += 256) {
        int j = idx >> 8;
        int rem = idx & 255;
        int s = rem >> 6;
        int l = rem & 63;
        int colw = j * 16 + (l & 15);
        int k0 = s * 32 + (l >> 4) * 8;
        half8 v;
        #pragma unroll
        for (int i = 0; i < 8; ++i)
            v[i] = (_Float16)Win[(k0 + i) * EMB + colw];
        Wf[j][s][l] = v;
    }
    if (t < EMB) bs[t] = bin[t];
    __syncthreads();

    int wid = t >> 6, lane = t & 63;
    int nt = blockIdx.x * 4 + wid;
    if (nt >= NTILES) return;
    int n0 = nt * 16;
    int arow = lane & 15, kg = lane >> 4;

    const float* xr = x + (size_t)(n0 + arow) * F_IN + kg * 8;
    half8 a[4];
    #pragma unroll
    for (int s = 0; s < 4; ++s) {
        f32x4 lo = *reinterpret_cast<const f32x4*>(xr + s * 32);
        f32x4 hi = *reinterpret_cast<const f32x4*>(xr + s * 32 + 4);
        half8 av;
        av[0] = (_Float16)lo[0]; av[1] = (_Float16)lo[1];
        av[2] = (_Float16)lo[2]; av[3] = (_Float16)lo[3];
        av[4] = (_Float16)hi[0]; av[5] = (_Float16)hi[1];
        av[6] = (_Float16)hi[2]; av[7] = (_Float16)hi[3];
        a[s] = av;
    }

    f32x4 c0 = {0.f, 0.f, 0.f, 0.f}, c1 = c0, c2 = c0;
    #pragma unroll
    for (int s = 0; s < 4; ++s) {
        c0 = __builtin_amdgcn_mfma_f32_16x16x32_f16(a[s], Wf[0][s][lane], c0, 0, 0, 0);
        c1 = __builtin_amdgcn_mfma_f32_16x16x32_f16(a[s], Wf[1][s][lane], c1, 0, 0, 0);
        c2 = __builtin_amdgcn_mfma_f32_16x16x32_f16(a[s], Wf[2][s][lane], c2, 0, 0, 0);
    }

    // epilogue: col = lane&15 (+16j), row = kg*4 + r
    int ccol = lane & 15;
    #pragma unroll
    for (int j = 0; j < 3; ++j) {
        int colg = j * 16 + ccol;
        float bias = bs[colg];
        f32x4 cj = (j == 0) ? c0 : (j == 1) ? c1 : c2;
        #pragma unroll
        for (int r = 0; r < 4; ++r) {
            int n = n0 + kg * 4 + r;
            float v = fmaxf(cj[r] + bias, 0.f);
            xf_out[(size_t)n * EMB + colg] = v;
            T0h[(size_t)n * TPAD + colg] = __float2half_rn(v);
        }
    }
    // zero pad cols 48..63: lane l -> node l>>2, halves 48 + (l&3)*4
    {
        int n = n0 + (lane >> 2);
        int cp = 48 + (lane & 3) * 4;
        *reinterpret_cast<uint2*>(T0h + (size_t)n * TPAD + cp) = make_uint2(0u, 0u);
    }
}

// ---- k=1 prop: T1 = prop(T0); out_acc = T0@W0 + T1@W1 (pure write) ----
__global__ __launch_bounds__(256) void prop_k1_kernel(
    const int* __restrict__ off, const uint2* __restrict__ edges,
    const __half* __restrict__ T0, __half* __restrict__ T1,
    const float* __restrict__ W0, const float* __restrict__ W1,
    float* __restrict__ out_acc)
{
    __shared__ float W0s[EMB * HID];    // 9216 B
    __shared__ float W1s[EMB * HID];    // 9216 B
    __shared__ float tdS[16][TPAD + 1];
    __shared__ float t0S[16][TPAD + 1];
    int t = threadIdx.x;
    for (int i = t; i < EMB * HID; i += 256) { W0s[i] = W0[i]; W1s[i] = W1[i]; }

    int grp = t >> 4, lane = t & 15;
    int g = blockIdx.x * 16 + grp;

    float a0 = 0.f, a1 = 0.f, a2 = 0.f, a3 = 0.f;
    int s = off[g], e = off[g + 1];
    int p = s;
    int e8 = s + ((e - s) & ~7);
    for (; p < e8; p += 8) {
        uint2 er[8];
        #pragma unroll
        for (int j = 0; j < 8; ++j) er[j] = edges[p + j];
        float ww[8]; uint2 hv[8];
        #pragma unroll
        for (int j = 0; j < 8; ++j) {
            const __half* tj = T0 + (size_t)er[j].x * TPAD;
            ww[j] = __uint_as_float(er[j].y);
            hv[j] = *reinterpret_cast<const uint2*>(tj + 4 * lane);
        }
        #pragma unroll
        for (int j = 0; j < 8; ++j) {
            __half2 h01 = *reinterpret_cast<__half2*>(&hv[j].x);
            __half2 h23 = *reinterpret_cast<__half2*>(&hv[j].y);
            a0 += ww[j] * __low2float(h01);
            a1 += ww[j] * __high2float(h01);
            a2 += ww[j] * __low2float(h23);
            a3 += ww[j] * __high2float(h23);
        }
    }
    for (; p < e; ++p) {
        uint2 er = edges[p];
        float wv = __uint_as_float(er.y);
        const __half* tr = T0 + (size_t)er.x * TPAD;
        uint2 hv = *reinterpret_cast<const uint2*>(tr + 4 * lane);
        __half2 h01 = *reinterpret_cast<__half2*>(&hv.x);
        __half2 h23 = *reinterpret_cast<__half2*>(&hv.y);
        a0 += wv * __low2float(h01);
        a1 += wv * __high2float(h01);
        a2 += wv * __low2float(h23);
        a3 += wv * __high2float(h23);
    }
    // write T1 (fp16) + stage T1, own T0 row in LDS
    {
        __half2 h01, h23;
        h01.x = __float2half_rn(a0); h01.y = __float2half_rn(a1);
        h23.x = __float2half_rn(a2); h23.y = __float2half_rn(a3);
        uint2 ov;
        ov.x = *reinterpret_cast<unsigned*>(&h01);
        ov.y = *reinterpret_cast<unsigned*>(&h23);
        *reinterpret_cast<uint2*>(T1 + (size_t)g * TPAD + 4 * lane) = ov;
    }
    tdS[grp][4 * lane]     = a0;
    tdS[grp][4 * lane + 1] = a1;
    tdS[grp][4 * lane + 2] = a2;
    tdS[grp][4 * lane + 3] = a3;
    {
        uint2 tv = *reinterpret_cast<const uint2*>(T0 + (size_t)g * TPAD + 4 * lane);
        __half2 t01 = *reinterpret_cast<__half2*>(&tv.x);
        __half2 t23 = *reinterpret_cast<__half2*>(&tv.y);
        t0S[grp][4 * lane]     = __low2float(t01);
        t0S[grp][4 * lane + 1] = __high2float(t01);
        t0S[grp][4 * lane + 2] = __low2float(t23);
        t0S[grp][4 * lane + 3] = __high2float(t23);
    }
    __syncthreads();

    float o0 = 0.f, o1 = 0.f, o2 = 0.f;
#pragma unroll 8
    for (int c = 0; c < EMB; ++c) {
        float t1v = tdS[grp][c];
        float t0v = t0S[grp][c];
        o0 += t1v * W1s[c * HID + lane]      + t0v * W0s[c * HID + lane];
        o1 += t1v * W1s[c * HID + lane + 16] + t0v * W0s[c * HID + lane + 16];
        o2 += t1v * W1s[c * HID + lane + 32] + t0v * W0s[c * HID + lane + 32];
    }
    float* orow = out_acc + (size_t)g * HID;
    orow[lane]      = o0;
    orow[lane + 16] = o1;
    orow[lane + 32] = o2;
}

// ---- k=2..5: T_k = 2*prop(T_{k-1}) - T_{k-2}; out_acc += T_k @ W_k ----
__global__ __launch_bounds__(256) void prop_fused_kernel(
    const int* __restrict__ off, const uint2* __restrict__ edges,
    const __half* __restrict__ tsrc, const __half* __restrict__ tprev,
    __half* __restrict__ tdst, const float* __restrict__ Wk,
    float* __restrict__ out_acc)
{
    __shared__ float Ws[EMB * HID];     // 9216 B
    __shared__ float tdS[16][TPAD + 1];
    int t = threadIdx.x;
    for (int i = t; i < EMB * HID; i += 256) Ws[i] = Wk[i];

    int grp = t >> 4, lane = t & 15;
    int g = blockIdx.x * 16 + grp;

    float a0 = 0.f, a1 = 0.f, a2 = 0.f, a3 = 0.f;
    int s = off[g], e = off[g + 1];
    int p = s;
    int e8 = s + ((e - s) & ~7);
    for (; p < e8; p += 8) {
        uint2 er[8];
        #pragma unroll
        for (int j = 0; j < 8; ++j) er[j] = edges[p + j];
        float ww[8]; uint2 hv[8];
        #pragma unroll
        for (int j = 0; j < 8; ++j) {
            const __half* tj = tsrc + (size_t)er[j].x * TPAD;
            ww[j] = __uint_as_float(er[j].y);
            hv[j] = *reinterpret_cast<const uint2*>(tj + 4 * lane);
        }
        #pragma unroll
        for (int j = 0; j < 8; ++j) {
            __half2 h01 = *reinterpret_cast<__half2*>(&hv[j].x);
            __half2 h23 = *reinterpret_cast<__half2*>(&hv[j].y);
            a0 += ww[j] * __low2float(h01);
            a1 += ww[j] * __high2float(h01);
            a2 += ww[j] * __low2float(h23);
            a3 += ww[j] * __high2float(h23);
        }
    }
    for (; p < e; ++p) {
        uint2 er = edges[p];
        float wv = __uint_as_float(er.y);
        const __half* tr = tsrc + (size_t)er.x * TPAD;
        uint2 hv = *reinterpret_cast<const uint2*>(tr + 4 * lane);
        __half2 h01 = *reinterpret_cast<__half2*>(&hv.x);
        __half2 h23 = *reinterpret_cast<__half2*>(&hv.y);
        a0 += wv * __low2float(h01);
        a1 += wv * __high2float(h01);
        a2 += wv * __low2float(h23);
        a3 += wv * __high2float(h23);
    }
    {
        uint2 tv = *reinterpret_cast<const uint2*>(tprev + (size_t)g * TPAD + 4 * lane);
        __half2 t01 = *reinterpret_cast<__half2*>(&tv.x);
        __half2 t23 = *reinterpret_cast<__half2*>(&tv.y);
        a0 = 2.f * a0 - __low2float(t01);
        a1 = 2.f * a1 - __high2float(t01);
        a2 = 2.f * a2 - __low2float(t23);
        a3 = 2.f * a3 - __high2float(t23);
    }
    {
        __half2 h01, h23;
        h01.x = __float2half_rn(a0); h01.y = __float2half_rn(a1);
        h23.x = __float2half_rn(a2); h23.y = __float2half_rn(a3);
        uint2 ov;
        ov.x = *reinterpret_cast<unsigned*>(&h01);
        ov.y = *reinterpret_cast<unsigned*>(&h23);
        *reinterpret_cast<uint2*>(tdst + (size_t)g * TPAD + 4 * lane) = ov;
    }
    tdS[grp][4 * lane]     = a0;
    tdS[grp][4 * lane + 1] = a1;
    tdS[grp][4 * lane + 2] = a2;
    tdS[grp][4 * lane + 3] = a3;
    __syncthreads();

    float o0 = 0.f, o1 = 0.f, o2 = 0.f;
#pragma unroll 8
    for (int c = 0; c < EMB; ++c) {
        float tv = tdS[grp][c];
        o0 += tv * Ws[c * HID + lane];
        o1 += tv * Ws[c * HID + lane + 16];
        o2 += tv * Ws[c * HID + lane + 32];
    }
    float* orow = out_acc + (size_t)g * HID;
    orow[lane]      += o0;
    orow[lane + 16] += o1;
    orow[lane + 32] += o2;
}

// ---- k=6 prop fused with final: y = relu(out_acc + T6@W6 + b_cheb) @ W_out + b_out ----
__global__ __launch_bounds__(256) void prop_final_kernel(
    const int* __restrict__ off, const uint2* __restrict__ edges,
    const __half* __restrict__ tsrc, const __half* __restrict__ tprev,
    const float* __restrict__ Wk, const float* __restrict__ out_acc,
    const float* __restrict__ bch, const float* __restrict__ Wout,
    const float* __restrict__ bout, float* __restrict__ y)
{
    __shared__ float Ws[EMB * HID];      // 9216 B
    __shared__ float Wo[HID * OUTF];     // 12288 B
    __shared__ float tdS[16][TPAD + 1];
    __shared__ float vS[16][HID + 1];
    __shared__ float bchS[HID];
    __shared__ float boS[OUTF];
    int t = threadIdx.x;
    for (int i = t; i < EMB * HID; i += 256) Ws[i] = Wk[i];
    for (int i = t; i < HID * OUTF; i += 256) Wo[i] = Wout[i];
    if (t < HID) bchS[t] = bch[t];
    if (t < OUTF) boS[t] = bout[t];

    int grp = t >> 4, lane = t & 15;
    int g = blockIdx.x * 16 + grp;

    float a0 = 0.f, a1 = 0.f, a2 = 0.f, a3 = 0.f;
    int s = off[g], e = off[g + 1];
    int p = s;
    int e8 = s + ((e - s) & ~7);
    for (; p < e8; p += 8) {
        uint2 er[8];
        #pragma unroll
        for (int j = 0; j < 8; ++j) er[j] = edges[p + j];
        float ww[8]; uint2 hv[8];
        #pragma unroll
        for (int j = 0; j < 8; ++j) {
            const __half* tj = tsrc + (size_t)er[j].x * TPAD;
            ww[j] = __uint_as_float(er[j].y);
            hv[j] = *reinterpret_cast<const uint2*>(tj + 4 * lane);
        }
        #pragma unroll
        for (int j = 0; j < 8; ++j) {
            __half2 h01 = *reinterpret_cast<__half2*>(&hv[j].x);
            __half2 h23 = *reinterpret_cast<__half2*>(&hv[j].y);
            a0 += ww[j] * __low2float(h01);
            a1 += ww[j] * __high2float(h01);
            a2 += ww[j] * __low2float(h23);
            a3 += ww[j] * __high2float(h23);
        }
    }
    for (; p < e; ++p) {
        uint2 er = edges[p];
        float wv = __uint_as_float(er.y);
        const __half* tr = tsrc + (size_t)er.x * TPAD;
        uint2 hv = *reinterpret_cast<const uint2*>(tr + 4 * lane);
        __half2 h01 = *reinterpret_cast<__half2*>(&hv.x);
        __half2 h23 = *reinterpret_cast<__half2*>(&hv.y);
        a0 += wv * __low2float(h01);
        a1 += wv * __high2float(h01);
        a2 += wv * __low2float(h23);
        a3 += wv * __high2float(h23);
    }
    {
        uint2 tv = *reinterpret_cast<const uint2*>(tprev + (size_t)g * TPAD + 4 * lane);
        __half2 t01 = *reinterpret_cast<__half2*>(&tv.x);
        __half2 t23 = *reinterpret_cast<__half2*>(&tv.y);
        a0 = 2.f * a0 - __low2float(t01);
        a1 = 2.f * a1 - __high2float(t01);
        a2 = 2.f * a2 - __low2float(t23);
        a3 = 2.f * a3 - __high2float(t23);
    }
    tdS[grp][4 * lane]     = a0;
    tdS[grp][4 * lane + 1] = a1;
    tdS[grp][4 * lane + 2] = a2;
    tdS[grp][4 * lane + 3] = a3;
    __syncthreads();

    float o0 = 0.f, o1 = 0.f, o2 = 0.f;
#pragma unroll 8
    for (int c = 0; c < EMB; ++c) {
        float tv = tdS[grp][c];
        o0 += tv * Ws[c * HID + lane];
        o1 += tv * Ws[c * HID + lane + 16];
        o2 += tv * Ws[c * HID + lane + 32];
    }
    const float* orow = out_acc + (size_t)g * HID;
    vS[grp][lane]      = fmaxf(orow[lane]      + o0 + bchS[lane],      0.f);
    vS[grp][lane + 16] = fmaxf(orow[lane + 16] + o1 + bchS[lane + 16], 0.f);
    vS[grp][lane + 32] = fmaxf(orow[lane + 32] + o2 + bchS[lane + 32], 0.f);

    float y0 = boS[4 * lane], y1 = boS[4 * lane + 1];
    float y2 = boS[4 * lane + 2], y3 = boS[4 * lane + 3];
#pragma unroll 8
    for (int h = 0; h < HID; ++h) {
        float v = vS[grp][h];
        float4 w4 = *reinterpret_cast<const float4*>(&Wo[h * OUTF + 4 * lane]);
        y0 += v * w4.x; y1 += v * w4.y; y2 += v * w4.z; y3 += v * w4.w;
    }
    *reinterpret_cast<float4*>(y + (size_t)g * OUTF + 4 * lane) =
        make_float4(y0, y1, y2, y3);
}

extern "C" void kernel_launch(void* const* d_in, const int* in_sizes, int n_in,
                              void* d_out, int out_size, void* d_ws, size_t ws_size,
                              hipStream_t stream)
{
    const float* x    = (const float*)d_in[0];
    const int*   ei   = (const int*)d_in[1];
    const float* ew   = (const float*)d_in[2];
    const float* Win  = (const float*)d_in[3];
    const float* bin  = (const float*)d_in[4];
    const float* Wch  = (const float*)d_in[5];   // [7,48,48]
    const float* bch  = (const float*)d_in[6];
    const float* Wout = (const float*)d_in[7];
    const float* bout = (const float*)d_in[8];

    const int* row = ei;
    const int* col = ei + N_EDGES;

    float* y_out  = (float*)d_out;                           // [N,64]
    float* xf_out = (float*)d_out + (size_t)N_NODES * OUTF;  // [N,48]

    char* p = (char*)d_ws;
    auto carve = [&](size_t bytes) {
        void* q = p;
        p += (bytes + 255) & ~(size_t)255;
        return q;
    };
    unsigned short* pc = (unsigned short*)carve((size_t)NR * BPR * RANGE * 2); // 6.4 MB
    float*    pd  = (float*)carve((size_t)NR * BPR * RANGE * 4);               // 12.8 MB
    float*    dinv = (float*)carve(N_NODES * 4);
    int*      off  = (int*)  carve((N_NODES + 1) * 4);
    int*      bsum = (int*)  carve(NBLK * 4);
    uint2*    edges = (uint2*)carve((size_t)N_EDGES * 8);
    float*    out_acc = (float*)carve((size_t)N_NODES * HID * 4);
    __half*   T0h = (__half*)carve((size_t)N_NODES * TPAD * 2);   // 6.4 MB each
    __half*   TAh = (__half*)carve((size_t)N_NODES * TPAD * 2);
    __half*   TBh = (__half*)carve((size_t)N_NODES * TPAD * 2);
    __half*   TCh = (__half*)carve((size_t)N_NODES * TPAD * 2);

    // graph preprocessing — zero global atomics, hierarchical scan
    hist_part_kernel<<<NR * BPR, HTHREADS, 0, stream>>>(row, col, ew, pc, pd);
    reduce_kernel<<<NBLK, 256, 0, stream>>>(pc, pd, dinv, off, bsum);
    bsum_scan_kernel<<<1, 256, 0, stream>>>(bsum, off);
    add_off_kernel<<<NBLK, 256, 0, stream>>>(off, bsum);
    scatter_part_kernel<<<NR * BPR, HTHREADS, 0, stream>>>(row, col, ew, dinv, off, pc, edges);

    // xf via MFMA -> f32 d_out tail + padded fp16 T0
    xf_mfma_kernel<<<(NTILES + 3) / 4, 256, 0, stream>>>(x, Win, bin, xf_out, T0h);

    const int prop_grid = NTILES;   // 3125

    // k=1: T1 = prop(T0); out_acc = T0@W0 + T1@W1 (write)
    prop_k1_kernel<<<prop_grid, 256, 0, stream>>>(off, edges, T0h, TAh,
                                                  Wch, Wch + EMB * HID, out_acc);
    // k=2..5 with fused GEMM — proven 3-buffer rotation.
    const __half* A = T0h;  // T_{k-2}
    __half*       B = TAh;  // T_{k-1}
    __half* bufs[3] = {TBh, TCh, TAh};
    for (int k = 2; k < KCH - 1; ++k) {
        __half* C = bufs[(k - 2) % 3];
        prop_fused_kernel<<<prop_grid, 256, 0, stream>>>(off, edges, B, A,
                                                         C, Wch + (size_t)k * EMB * HID, out_acc);
        A = B; B = C;
    }
    // k=6: fused prop + final
    prop_final_kernel<<<prop_grid, 256, 0, stream>>>(off, edges, B, A,
                                                     Wch + (size_t)(KCH - 1) * EMB * HID,
                                                     out_acc, bch, Wout, bout, y_out);
}

// Round 14
// 342.512 us; speedup vs baseline: 1.2701x; 1.0251x over previous
//
#include <hip/hip_runtime.h>
#include <hip/hip_fp16.h>

#define N_NODES 50000
#define N_EDGES 1600000
#define F_IN    128
#define EMB     48
#define HID     48
#define OUTF    64
#define KCH     7
#define TPAD    64                   // padded T row length (halves) = 128 B

#define NR    8                      // node ranges (LDS partitions)
#define RANGE (N_NODES / NR)         // 6250 counters
#define BPR   64                     // edge slices
#define SLICE (N_EDGES / BPR)        // 25000 edges per slice (div by 4)
#define HTHREADS 512
#define NBLK  ((N_NODES + 255) / 256)   // 196 reduce blocks
#define NTILES (N_NODES / 16)        // 3125 node tiles

typedef __attribute__((ext_vector_type(8))) _Float16 half8;
typedef __attribute__((ext_vector_type(4))) float f32x4;

// ---- gather+accumulate macro body (lane<12 only), unroll-16 / 4 / scalar ----
#define PROP_GATHER_LOOP(TSRC)                                                  \
    {                                                                           \
        int e16 = s + ((e - s) & ~15);                                          \
        for (; p < e16; p += 16) {                                              \
            float ww[16]; uint2 hv[16];                                         \
            _Pragma("unroll")                                                   \
            for (int j = 0; j < 16; ++j) {                                      \
                uint2 er = edges[p + j];                                        \
                ww[j] = __uint_as_float(er.y);                                  \
                hv[j] = *reinterpret_cast<const uint2*>(                        \
                    TSRC + (size_t)er.x * TPAD + 4 * lane);                     \
            }                                                                   \
            _Pragma("unroll")                                                   \
            for (int j = 0; j < 16; ++j) {                                      \
                __half2 h01 = *reinterpret_cast<__half2*>(&hv[j].x);            \
                __half2 h23 = *reinterpret_cast<__half2*>(&hv[j].y);            \
                a0 += ww[j] * __low2float(h01);                                 \
                a1 += ww[j] * __high2float(h01);                                \
                a2 += ww[j] * __low2float(h23);                                 \
                a3 += ww[j] * __high2float(h23);                                \
            }                                                                   \
        }                                                                       \
        int e4b = p + ((e - p) & ~3);                                           \
        for (; p < e4b; p += 4) {                                               \
            float ww[4]; uint2 hv[4];                                           \
            _Pragma("unroll")                                                   \
            for (int j = 0; j < 4; ++j) {                                       \
                uint2 er = edges[p + j];                                        \
                ww[j] = __uint_as_float(er.y);                                  \
                hv[j] = *reinterpret_cast<const uint2*>(                        \
                    TSRC + (size_t)er.x * TPAD + 4 * lane);                     \
            }                                                                   \
            _Pragma("unroll")                                                   \
            for (int j = 0; j < 4; ++j) {                                       \
                __half2 h01 = *reinterpret_cast<__half2*>(&hv[j].x);            \
                __half2 h23 = *reinterpret_cast<__half2*>(&hv[j].y);            \
                a0 += ww[j] * __low2float(h01);                                 \
                a1 += ww[j] * __high2float(h01);                                \
                a2 += ww[j] * __low2float(h23);                                 \
                a3 += ww[j] * __high2float(h23);                                \
            }                                                                   \
        }                                                                       \
        for (; p < e; ++p) {                                                    \
            uint2 er = edges[p];                                                \
            float wv = __uint_as_float(er.y);                                   \
            uint2 hv = *reinterpret_cast<const uint2*>(                         \
                TSRC + (size_t)er.x * TPAD + 4 * lane);                         \
            __half2 h01 = *reinterpret_cast<__half2*>(&hv.x);                   \
            __half2 h23 = *reinterpret_cast<__half2*>(&hv.y);                   \
            a0 += wv * __low2float(h01);                                        \
            a1 += wv * __high2float(h01);                                       \
            a2 += wv * __low2float(h23);                                        \
            a3 += wv * __high2float(h23);                                       \
        }                                                                       \
    }

// ---- pass A: partitioned LDS histogram (cnt by col packed u16, deg by row f32) ----
__global__ __launch_bounds__(HTHREADS) void hist_part_kernel(
    const int* __restrict__ row, const int* __restrict__ col,
    const float* __restrict__ w,
    unsigned short* __restrict__ pc, float* __restrict__ pd)
{
    __shared__ unsigned lc32[RANGE / 2];  // 12.5 KB, 2 u16 counters per word
    __shared__ float    ld[RANGE];        // 25 KB
    int t = threadIdx.x;
    for (int i = t; i < RANGE / 2; i += HTHREADS) lc32[i] = 0u;
    for (int i = t; i < RANGE; i += HTHREADS) ld[i] = 0.f;
    __syncthreads();
    int r = blockIdx.x / BPR;        // node range
    int b = blockIdx.x % BPR;        // edge slice
    int base = r * RANGE;
    int lo = b * SLICE;
    for (int e0 = lo + t * 4; e0 < lo + SLICE; e0 += HTHREADS * 4) {
        int4   c4 = *(const int4*)&col[e0];
        int4   r4 = *(const int4*)&row[e0];
        float4 w4 = *(const float4*)&w[e0];
        int ci, ri;
        ci = c4.x - base; if ((unsigned)ci < RANGE) atomicAdd(&lc32[ci >> 1], 1u << ((ci & 1) * 16));
        ri = r4.x - base; if ((unsigned)ri < RANGE) atomicAdd(&ld[ri], w4.x);
        ci = c4.y - base; if ((unsigned)ci < RANGE) atomicAdd(&lc32[ci >> 1], 1u << ((ci & 1) * 16));
        ri = r4.y - base; if ((unsigned)ri < RANGE) atomicAdd(&ld[ri], w4.y);
        ci = c4.z - base; if ((unsigned)ci < RANGE) atomicAdd(&lc32[ci >> 1], 1u << ((ci & 1) * 16));
        ri = r4.z - base; if ((unsigned)ri < RANGE) atomicAdd(&ld[ri], w4.z);
        ci = c4.w - base; if ((unsigned)ci < RANGE) atomicAdd(&lc32[ci >> 1], 1u << ((ci & 1) * 16));
        ri = r4.w - base; if ((unsigned)ri < RANGE) atomicAdd(&ld[ri], w4.w);
    }
    __syncthreads();
    unsigned short* pcb = pc + (size_t)blockIdx.x * RANGE;
    float*          pdb = pd + (size_t)blockIdx.x * RANGE;
    for (int i = t; i < RANGE; i += HTHREADS) {
        pcb[i] = (unsigned short)((lc32[i >> 1] >> ((i & 1) * 16)) & 0xFFFFu);
        pdb[i] = ld[i];
    }
}

// ---- fold partials: dinv, per-slice prefix (pc in place), intra-block scan ----
__global__ __launch_bounds__(256) void reduce_kernel(
    unsigned short* __restrict__ pc, const float* __restrict__ pd,
    float* __restrict__ dinv, int* __restrict__ off, int* __restrict__ bsum)
{
    int t = threadIdx.x;
    int n = blockIdx.x * 256 + t;
    int c = 0; float d = 0.f;
    if (n < N_NODES) {
        int r = n / RANGE, i = n - r * RANGE;
        size_t base = (size_t)r * BPR * RANGE + i;
        unsigned csum = 0;
        for (int b = 0; b < BPR; ++b) {
            size_t idx = base + (size_t)b * RANGE;
            unsigned x = pc[idx];
            pc[idx] = (unsigned short)csum;
            csum += x;
            d += pd[idx];
        }
        c = (int)csum;
        dinv[n] = d > 0.f ? rsqrtf(d) : 0.f;
    }
    int lane = t & 63, wid = t >> 6;
    int v = c;
    for (int s = 1; s < 64; s <<= 1) {
        int u = __shfl_up(v, s);
        if (lane >= s) v += u;
    }
    __shared__ int ws[4];
    if (lane == 63) ws[wid] = v;
    __syncthreads();
    int wb = 0;
    for (int i = 0; i < 4; ++i) if (i < wid) wb += ws[i];
    int ex = (v - c) + wb;
    if (n < N_NODES) off[n] = ex;
    if (t == 255) bsum[blockIdx.x] = ex + c;
}

// ---- exclusive scan of 196 block sums ----
__global__ __launch_bounds__(256) void bsum_scan_kernel(
    int* __restrict__ bsum, int* __restrict__ off)
{
    int t = threadIdx.x;
    int orig = (t < NBLK) ? bsum[t] : 0;
    int lane = t & 63, wid = t >> 6;
    int v = orig;
    for (int s = 1; s < 64; s <<= 1) {
        int u = __shfl_up(v, s);
        if (lane >= s) v += u;
    }
    __shared__ int ws[4];
    if (lane == 63) ws[wid] = v;
    __syncthreads();
    int wb = 0;
    for (int i = 0; i < 4; ++i) if (i < wid) wb += ws[i];
    int ex = (v - orig) + wb;
    if (t < NBLK) bsum[t] = ex;
    if (t == NBLK - 1) off[N_NODES] = ex + orig;
}

// ---- add block prefix back ----
__global__ __launch_bounds__(256) void add_off_kernel(
    int* __restrict__ off, const int* __restrict__ bsum)
{
    int n = blockIdx.x * 256 + threadIdx.x;
    if (n < N_NODES) off[n] += bsum[n >> 8];
}

// ---- pass D: scatter via re-derived LDS ranks — zero global atomics ----
__global__ __launch_bounds__(HTHREADS) void scatter_part_kernel(
    const int* __restrict__ row, const int* __restrict__ col,
    const float* __restrict__ w, const float* __restrict__ dinv,
    const int* __restrict__ off, const unsigned short* __restrict__ pc,
    uint2* __restrict__ edges)
{
    __shared__ unsigned lc32[RANGE / 2];  // 12.5 KB
    int t = threadIdx.x;
    for (int i = t; i < RANGE / 2; i += HTHREADS) lc32[i] = 0u;
    __syncthreads();
    int r = blockIdx.x / BPR;
    int b = blockIdx.x % BPR;
    int base = r * RANGE;
    int lo = b * SLICE;
    const unsigned short* pcb = pc + (size_t)blockIdx.x * RANGE;
    for (int e0 = lo + t * 4; e0 < lo + SLICE; e0 += HTHREADS * 4) {
        int4   c4 = *(const int4*)&col[e0];
        int4   r4 = *(const int4*)&row[e0];
        float4 w4 = *(const float4*)&w[e0];
        #pragma unroll
        for (int j = 0; j < 4; ++j) {
            int c  = (j == 0) ? c4.x : (j == 1) ? c4.y : (j == 2) ? c4.z : c4.w;
            int rw = (j == 0) ? r4.x : (j == 1) ? r4.y : (j == 2) ? r4.z : r4.w;
            float we = (j == 0) ? w4.x : (j == 1) ? w4.y : (j == 2) ? w4.z : w4.w;
            int ci = c - base;
            if ((unsigned)ci < RANGE) {
                unsigned old = atomicAdd(&lc32[ci >> 1], 1u << ((ci & 1) * 16));
                unsigned lrank = (old >> ((ci & 1) * 16)) & 0xFFFFu;
                float nr = -dinv[rw] * we * dinv[c];
                int pos = off[c] + (int)pcb[ci] + (int)lrank;
                edges[pos] = make_uint2((unsigned)rw, __float_as_uint(nr));
            }
        }
    }
}

// ---- MFMA xf: xf = relu(x @ W_in + b_in), one wave per 16-node tile ----
__global__ __launch_bounds__(256) void xf_mfma_kernel(
    const float* __restrict__ x, const float* __restrict__ Win,
    const float* __restrict__ bin, float* __restrict__ xf_out,
    __half* __restrict__ T0h)
{
    __shared__ half8 Wf[3][4][64];   // 12288 B
    __shared__ float bs[EMB];
    int t = threadIdx.x;
    for (int idx = t; idx < 3 * 4 * 64; idx += 256) {
        int j = idx >> 8;
        int rem = idx & 255;
        int s = rem >> 6;
        int l = rem & 63;
        int colw = j * 16 + (l & 15);
        int k0 = s * 32 + (l >> 4) * 8;
        half8 v;
        #pragma unroll
        for (int i = 0; i < 8; ++i)
            v[i] = (_Float16)Win[(k0 + i) * EMB + colw];
        Wf[j][s][l] = v;
    }
    if (t < EMB) bs[t] = bin[t];
    __syncthreads();

    int wid = t >> 6, lane = t & 63;
    int nt = blockIdx.x * 4 + wid;
    if (nt >= NTILES) return;
    int n0 = nt * 16;
    int arow = lane & 15, kg = lane >> 4;

    const float* xr = x + (size_t)(n0 + arow) * F_IN + kg * 8;
    half8 a[4];
    #pragma unroll
    for (int s = 0; s < 4; ++s) {
        f32x4 lo = *reinterpret_cast<const f32x4*>(xr + s * 32);
        f32x4 hi = *reinterpret_cast<const f32x4*>(xr + s * 32 + 4);
        half8 av;
        av[0] = (_Float16)lo[0]; av[1] = (_Float16)lo[1];
        av[2] = (_Float16)lo[2]; av[3] = (_Float16)lo[3];
        av[4] = (_Float16)hi[0]; av[5] = (_Float16)hi[1];
        av[6] = (_Float16)hi[2]; av[7] = (_Float16)hi[3];
        a[s] = av;
    }

    f32x4 c0 = {0.f, 0.f, 0.f, 0.f}, c1 = c0, c2 = c0;
    #pragma unroll
    for (int s = 0; s < 4; ++s) {
        c0 = __builtin_amdgcn_mfma_f32_16x16x32_f16(a[s], Wf[0][s][lane], c0, 0, 0, 0);
        c1 = __builtin_amdgcn_mfma_f32_16x16x32_f16(a[s], Wf[1][s][lane], c1, 0, 0, 0);
        c2 = __builtin_amdgcn_mfma_f32_16x16x32_f16(a[s], Wf[2][s][lane], c2, 0, 0, 0);
    }

    int ccol = lane & 15;
    #pragma unroll
    for (int j = 0; j < 3; ++j) {
        int colg = j * 16 + ccol;
        float bias = bs[colg];
        f32x4 cj = (j == 0) ? c0 : (j == 1) ? c1 : c2;
        #pragma unroll
        for (int r = 0; r < 4; ++r) {
            int n = n0 + kg * 4 + r;
            float v = fmaxf(cj[r] + bias, 0.f);
            xf_out[(size_t)n * EMB + colg] = v;
            T0h[(size_t)n * TPAD + colg] = __float2half_rn(v);
        }
    }
    {
        int n = n0 + (lane >> 2);
        int cp = 48 + (lane & 3) * 4;
        *reinterpret_cast<uint2*>(T0h + (size_t)n * TPAD + cp) = make_uint2(0u, 0u);
    }
}

// ---- k=1 prop: T1 = prop(T0); out_acc = T0@W0 + T1@W1 (pure write) ----
__global__ __launch_bounds__(256) void prop_k1_kernel(
    const int* __restrict__ off, const uint2* __restrict__ edges,
    const __half* __restrict__ T0, __half* __restrict__ T1,
    const float* __restrict__ W0, const float* __restrict__ W1,
    float* __restrict__ out_acc)
{
    __shared__ float W0s[EMB * HID];    // 9216 B
    __shared__ float W1s[EMB * HID];    // 9216 B
    __shared__ float tdS[16][EMB + 1];
    __shared__ float t0S[16][EMB + 1];
    int t = threadIdx.x;
    for (int i = t; i < EMB * HID; i += 256) { W0s[i] = W0[i]; W1s[i] = W1[i]; }

    int grp = t >> 4, lane = t & 15;
    int g = blockIdx.x * 16 + grp;

    float a0 = 0.f, a1 = 0.f, a2 = 0.f, a3 = 0.f;
    if (lane < 12) {
        int s = off[g], e = off[g + 1];
        int p = s;
        PROP_GATHER_LOOP(T0)
        uint2 tv = *reinterpret_cast<const uint2*>(T0 + (size_t)g * TPAD + 4 * lane);
        __half2 t01 = *reinterpret_cast<__half2*>(&tv.x);
        __half2 t23 = *reinterpret_cast<__half2*>(&tv.y);
        t0S[grp][4 * lane]     = __low2float(t01);
        t0S[grp][4 * lane + 1] = __high2float(t01);
        t0S[grp][4 * lane + 2] = __low2float(t23);
        t0S[grp][4 * lane + 3] = __high2float(t23);
        tdS[grp][4 * lane]     = a0;
        tdS[grp][4 * lane + 1] = a1;
        tdS[grp][4 * lane + 2] = a2;
        tdS[grp][4 * lane + 3] = a3;
    }
    {
        __half2 h01, h23;
        h01.x = __float2half_rn(a0); h01.y = __float2half_rn(a1);
        h23.x = __float2half_rn(a2); h23.y = __float2half_rn(a3);
        uint2 ov;
        ov.x = *reinterpret_cast<unsigned*>(&h01);
        ov.y = *reinterpret_cast<unsigned*>(&h23);
        *reinterpret_cast<uint2*>(T1 + (size_t)g * TPAD + 4 * lane) = ov;
    }
    __syncthreads();

    float o0 = 0.f, o1 = 0.f, o2 = 0.f;
#pragma unroll 8
    for (int c = 0; c < EMB; ++c) {
        float t1v = tdS[grp][c];
        float t0v = t0S[grp][c];
        o0 += t1v * W1s[c * HID + lane]      + t0v * W0s[c * HID + lane];
        o1 += t1v * W1s[c * HID + lane + 16] + t0v * W0s[c * HID + lane + 16];
        o2 += t1v * W1s[c * HID + lane + 32] + t0v * W0s[c * HID + lane + 32];
    }
    float* orow = out_acc + (size_t)g * HID;
    orow[lane]      = o0;
    orow[lane + 16] = o1;
    orow[lane + 32] = o2;
}

// ---- k=2..5: T_k = 2*prop(T_{k-1}) - T_{k-2}; out_acc += T_k @ W_k ----
__global__ __launch_bounds__(256) void prop_fused_kernel(
    const int* __restrict__ off, const uint2* __restrict__ edges,
    const __half* __restrict__ tsrc, const __half* __restrict__ tprev,
    __half* __restrict__ tdst, const float* __restrict__ Wk,
    float* __restrict__ out_acc)
{
    __shared__ float Ws[EMB * HID];     // 9216 B
    __shared__ float tdS[16][EMB + 1];
    int t = threadIdx.x;
    for (int i = t; i < EMB * HID; i += 256) Ws[i] = Wk[i];

    int grp = t >> 4, lane = t & 15;
    int g = blockIdx.x * 16 + grp;

    float a0 = 0.f, a1 = 0.f, a2 = 0.f, a3 = 0.f;
    if (lane < 12) {
        int s = off[g], e = off[g + 1];
        int p = s;
        PROP_GATHER_LOOP(tsrc)
        uint2 tv = *reinterpret_cast<const uint2*>(tprev + (size_t)g * TPAD + 4 * lane);
        __half2 t01 = *reinterpret_cast<__half2*>(&tv.x);
        __half2 t23 = *reinterpret_cast<__half2*>(&tv.y);
        a0 = 2.f * a0 - __low2float(t01);
        a1 = 2.f * a1 - __high2float(t01);
        a2 = 2.f * a2 - __low2float(t23);
        a3 = 2.f * a3 - __high2float(t23);
        tdS[grp][4 * lane]     = a0;
        tdS[grp][4 * lane + 1] = a1;
        tdS[grp][4 * lane + 2] = a2;
        tdS[grp][4 * lane + 3] = a3;
    }
    {
        __half2 h01, h23;
        h01.x = __float2half_rn(a0); h01.y = __float2half_rn(a1);
        h23.x = __float2half_rn(a2); h23.y = __float2half_rn(a3);
        uint2 ov;
        ov.x = *reinterpret_cast<unsigned*>(&h01);
        ov.y = *reinterpret_cast<unsigned*>(&h23);
        *reinterpret_cast<uint2*>(tdst + (size_t)g * TPAD + 4 * lane) = ov;
    }
    __syncthreads();

    float o0 = 0.f, o1 = 0.f, o2 = 0.f;
#pragma unroll 8
    for (int c = 0; c < EMB; ++c) {
        float tv = tdS[grp][c];
        o0 += tv * Ws[c * HID + lane];
        o1 += tv * Ws[c * HID + lane + 16];
        o2 += tv * Ws[c * HID + lane + 32];
    }
    float* orow = out_acc + (size_t)g * HID;
    orow[lane]      += o0;
    orow[lane + 16] += o1;
    orow[lane + 32] += o2;
}

// ---- k=6 prop fused with final: y = relu(out_acc + T6@W6 + b_cheb) @ W_out + b_out ----
__global__ __launch_bounds__(256) void prop_final_kernel(
    const int* __restrict__ off, const uint2* __restrict__ edges,
    const __half* __restrict__ tsrc, const __half* __restrict__ tprev,
    const float* __restrict__ Wk, const float* __restrict__ out_acc,
    const float* __restrict__ bch, const float* __restrict__ Wout,
    const float* __restrict__ bout, float* __restrict__ y)
{
    __shared__ float Ws[EMB * HID];      // 9216 B
    __shared__ float Wo[HID * OUTF];     // 12288 B
    __shared__ float tdS[16][EMB + 1];
    __shared__ float vS[16][HID + 1];
    __shared__ float bchS[HID];
    __shared__ float boS[OUTF];
    int t = threadIdx.x;
    for (int i = t; i < EMB * HID; i += 256) Ws[i] = Wk[i];
    for (int i = t; i < HID * OUTF; i += 256) Wo[i] = Wout[i];
    if (t < HID) bchS[t] = bch[t];
    if (t < OUTF) boS[t] = bout[t];

    int grp = t >> 4, lane = t & 15;
    int g = blockIdx.x * 16 + grp;

    float a0 = 0.f, a1 = 0.f, a2 = 0.f, a3 = 0.f;
    if (lane < 12) {
        int s = off[g], e = off[g + 1];
        int p = s;
        PROP_GATHER_LOOP(tsrc)
        uint2 tv = *reinterpret_cast<const uint2*>(tprev + (size_t)g * TPAD + 4 * lane);
        __half2 t01 = *reinterpret_cast<__half2*>(&tv.x);
        __half2 t23 = *reinterpret_cast<__half2*>(&tv.y);
        a0 = 2.f * a0 - __low2float(t01);
        a1 = 2.f * a1 - __high2float(t01);
        a2 = 2.f * a2 - __low2float(t23);
        a3 = 2.f * a3 - __high2float(t23);
        tdS[grp][4 * lane]     = a0;
        tdS[grp][4 * lane + 1] = a1;
        tdS[grp][4 * lane + 2] = a2;
        tdS[grp][4 * lane + 3] = a3;
    }
    __syncthreads();

    float o0 = 0.f, o1 = 0.f, o2 = 0.f;
#pragma unroll 8
    for (int c = 0; c < EMB; ++c) {
        float tv = tdS[grp][c];
        o0 += tv * Ws[c * HID + lane];
        o1 += tv * Ws[c * HID + lane + 16];
        o2 += tv * Ws[c * HID + lane + 32];
    }
    const float* orow = out_acc + (size_t)g * HID;
    vS[grp][lane]      = fmaxf(orow[lane]      + o0 + bchS[lane],      0.f);
    vS[grp][lane + 16] = fmaxf(orow[lane + 16] + o1 + bchS[lane + 16], 0.f);
    vS[grp][lane + 32] = fmaxf(orow[lane + 32] + o2 + bchS[lane + 32], 0.f);

    float y0 = boS[4 * lane], y1 = boS[4 * lane + 1];
    float y2 = boS[4 * lane + 2], y3 = boS[4 * lane + 3];
#pragma unroll 8
    for (int h = 0; h < HID; ++h) {
        float v = vS[grp][h];
        float4 w4 = *reinterpret_cast<const float4*>(&Wo[h * OUTF + 4 * lane]);
        y0 += v * w4.x; y1 += v * w4.y; y2 += v * w4.z; y3 += v * w4.w;
    }
    *reinterpret_cast<float4*>(y + (size_t)g * OUTF + 4 * lane) =
        make_float4(y0, y1, y2, y3);
}

extern "C" void kernel_launch(void* const* d_in, const int* in_sizes, int n_in,
                              void* d_out, int out_size, void* d_ws, size_t ws_size,
                              hipStream_t stream)
{
    const float* x    = (const float*)d_in[0];
    const int*   ei   = (const int*)d_in[1];
    const float* ew   = (const float*)d_in[2];
    const float* Win  = (const float*)d_in[3];
    const float* bin  = (const float*)d_in[4];
    const float* Wch  = (const float*)d_in[5];   // [7,48,48]
    const float* bch  = (const float*)d_in[6];
    const float* Wout = (const float*)d_in[7];
    const float* bout = (const float*)d_in[8];

    const int* row = ei;
    const int* col = ei + N_EDGES;

    float* y_out  = (float*)d_out;                           // [N,64]
    float* xf_out = (float*)d_out + (size_t)N_NODES * OUTF;  // [N,48]

    char* p = (char*)d_ws;
    auto carve = [&](size_t bytes) {
        void* q = p;
        p += (bytes + 255) & ~(size_t)255;
        return q;
    };
    unsigned short* pc = (unsigned short*)carve((size_t)NR * BPR * RANGE * 2); // 6.4 MB
    float*    pd  = (float*)carve((size_t)NR * BPR * RANGE * 4);               // 12.8 MB
    float*    dinv = (float*)carve(N_NODES * 4);
    int*      off  = (int*)  carve((N_NODES + 1) * 4);
    int*      bsum = (int*)  carve(NBLK * 4);
    uint2*    edges = (uint2*)carve((size_t)N_EDGES * 8);
    float*    out_acc = (float*)carve((size_t)N_NODES * HID * 4);
    __half*   T0h = (__half*)carve((size_t)N_NODES * TPAD * 2);   // 6.4 MB each
    __half*   TAh = (__half*)carve((size_t)N_NODES * TPAD * 2);
    __half*   TBh = (__half*)carve((size_t)N_NODES * TPAD * 2);
    __half*   TCh = (__half*)carve((size_t)N_NODES * TPAD * 2);

    // graph preprocessing — zero global atomics, hierarchical scan
    hist_part_kernel<<<NR * BPR, HTHREADS, 0, stream>>>(row, col, ew, pc, pd);
    reduce_kernel<<<NBLK, 256, 0, stream>>>(pc, pd, dinv, off, bsum);
    bsum_scan_kernel<<<1, 256, 0, stream>>>(bsum, off);
    add_off_kernel<<<NBLK, 256, 0, stream>>>(off, bsum);
    scatter_part_kernel<<<NR * BPR, HTHREADS, 0, stream>>>(row, col, ew, dinv, off, pc, edges);

    // xf via MFMA -> f32 d_out tail + padded fp16 T0
    xf_mfma_kernel<<<(NTILES + 3) / 4, 256, 0, stream>>>(x, Win, bin, xf_out, T0h);

    const int prop_grid = NTILES;   // 3125

    // k=1: T1 = prop(T0); out_acc = T0@W0 + T1@W1 (write)
    prop_k1_kernel<<<prop_grid, 256, 0, stream>>>(off, edges, T0h, TAh,
                                                  Wch, Wch + EMB * HID, out_acc);
    // k=2..5 with fused GEMM — proven 3-buffer rotation.
    const __half* A = T0h;  // T_{k-2}
    __half*       B = TAh;  // T_{k-1}
    __half* bufs[3] = {TBh, TCh, TAh};
    for (int k = 2; k < KCH - 1; ++k) {
        __half* C = bufs[(k - 2) % 3];
        prop_fused_kernel<<<prop_grid, 256, 0, stream>>>(off, edges, B, A,
                                                         C, Wch + (size_t)k * EMB * HID, out_acc);
        A = B; B = C;
    }
    // k=6: fused prop + final
    prop_final_kernel<<<prop_grid, 256, 0, stream>>>(off, edges, B, A,
                                                     Wch + (size_t)(KCH - 1) * EMB * HID,
                                                     out_acc, bch, Wout, bout, y_out);
}

// Round 15
// 338.746 us; speedup vs baseline: 1.2843x; 1.0111x over previous
//
#include <hip/hip_runtime.h>
#include <hip/hip_fp16.h>

#define N_NODES 50000
#define N_EDGES 1600000
#define F_IN    128
#define EMB     48
#define HID     48
#define OUTF    64
#define KCH     7
#define TPAD    64                   // padded T row length (halves) = 128 B

#define NR    8                      // node ranges (LDS partitions)
#define RANGE (N_NODES / NR)         // 6250 counters
#define BPR   64                     // edge slices
#define SLICE (N_EDGES / BPR)        // 25000 edges per slice (div by 4)
#define HTHREADS 512
#define NBLK  ((N_NODES + 255) / 256)   // 196 reduce blocks
#define NTILES (N_NODES / 16)        // 3125 node tiles

typedef __attribute__((ext_vector_type(8))) _Float16 half8;
typedef __attribute__((ext_vector_type(4))) float f32x4;

// ---- gather+accumulate macro body (lane<12 only), unroll-16 / 4 / scalar ----
#define PROP_GATHER_LOOP(TSRC)                                                  \
    {                                                                           \
        int e16 = s + ((e - s) & ~15);                                          \
        for (; p < e16; p += 16) {                                              \
            float ww[16]; uint2 hv[16];                                         \
            _Pragma("unroll")                                                   \
            for (int j = 0; j < 16; ++j) {                                      \
                uint2 er = edges[p + j];                                        \
                ww[j] = __uint_as_float(er.y);                                  \
                hv[j] = *reinterpret_cast<const uint2*>(                        \
                    TSRC + (size_t)er.x * TPAD + 4 * lane);                     \
            }                                                                   \
            _Pragma("unroll")                                                   \
            for (int j = 0; j < 16; ++j) {                                      \
                __half2 h01 = *reinterpret_cast<__half2*>(&hv[j].x);            \
                __half2 h23 = *reinterpret_cast<__half2*>(&hv[j].y);            \
                a0 += ww[j] * __low2float(h01);                                 \
                a1 += ww[j] * __high2float(h01);                                \
                a2 += ww[j] * __low2float(h23);                                 \
                a3 += ww[j] * __high2float(h23);                                \
            }                                                                   \
        }                                                                       \
        int e4b = p + ((e - p) & ~3);                                           \
        for (; p < e4b; p += 4) {                                               \
            float ww[4]; uint2 hv[4];                                           \
            _Pragma("unroll")                                                   \
            for (int j = 0; j < 4; ++j) {                                       \
                uint2 er = edges[p + j];                                        \
                ww[j] = __uint_as_float(er.y);                                  \
                hv[j] = *reinterpret_cast<const uint2*>(                        \
                    TSRC + (size_t)er.x * TPAD + 4 * lane);                     \
            }                                                                   \
            _Pragma("unroll")                                                   \
            for (int j = 0; j < 4; ++j) {                                       \
                __half2 h01 = *reinterpret_cast<__half2*>(&hv[j].x);            \
                __half2 h23 = *reinterpret_cast<__half2*>(&hv[j].y);            \
                a0 += ww[j] * __low2float(h01);                                 \
                a1 += ww[j] * __high2float(h01);                                \
                a2 += ww[j] * __low2float(h23);                                 \
                a3 += ww[j] * __high2float(h23);                                \
            }                                                                   \
        }                                                                       \
        for (; p < e; ++p) {                                                    \
            uint2 er = edges[p];                                                \
            float wv = __uint_as_float(er.y);                                   \
            uint2 hv = *reinterpret_cast<const uint2*>(                         \
                TSRC + (size_t)er.x * TPAD + 4 * lane);                         \
            __half2 h01 = *reinterpret_cast<__half2*>(&hv.x);                   \
            __half2 h23 = *reinterpret_cast<__half2*>(&hv.y);                   \
            a0 += wv * __low2float(h01);                                        \
            a1 += wv * __high2float(h01);                                       \
            a2 += wv * __low2float(h23);                                        \
            a3 += wv * __high2float(h23);                                       \
        }                                                                       \
    }

// ---- pass A: partitioned LDS histogram (cnt by col packed u16, deg by row f32) ----
__global__ __launch_bounds__(HTHREADS) void hist_part_kernel(
    const int* __restrict__ row, const int* __restrict__ col,
    const float* __restrict__ w,
    unsigned short* __restrict__ pc, float* __restrict__ pd)
{
    __shared__ unsigned lc32[RANGE / 2];  // 12.5 KB, 2 u16 counters per word
    __shared__ float    ld[RANGE];        // 25 KB
    int t = threadIdx.x;
    for (int i = t; i < RANGE / 2; i += HTHREADS) lc32[i] = 0u;
    for (int i = t; i < RANGE; i += HTHREADS) ld[i] = 0.f;
    __syncthreads();
    int r = blockIdx.x / BPR;        // node range
    int b = blockIdx.x % BPR;        // edge slice
    int base = r * RANGE;
    int lo = b * SLICE;
    for (int e0 = lo + t * 4; e0 < lo + SLICE; e0 += HTHREADS * 4) {
        int4   c4 = *(const int4*)&col[e0];
        int4   r4 = *(const int4*)&row[e0];
        float4 w4 = *(const float4*)&w[e0];
        int ci, ri;
        ci = c4.x - base; if ((unsigned)ci < RANGE) atomicAdd(&lc32[ci >> 1], 1u << ((ci & 1) * 16));
        ri = r4.x - base; if ((unsigned)ri < RANGE) atomicAdd(&ld[ri], w4.x);
        ci = c4.y - base; if ((unsigned)ci < RANGE) atomicAdd(&lc32[ci >> 1], 1u << ((ci & 1) * 16));
        ri = r4.y - base; if ((unsigned)ri < RANGE) atomicAdd(&ld[ri], w4.y);
        ci = c4.z - base; if ((unsigned)ci < RANGE) atomicAdd(&lc32[ci >> 1], 1u << ((ci & 1) * 16));
        ri = r4.z - base; if ((unsigned)ri < RANGE) atomicAdd(&ld[ri], w4.z);
        ci = c4.w - base; if ((unsigned)ci < RANGE) atomicAdd(&lc32[ci >> 1], 1u << ((ci & 1) * 16));
        ri = r4.w - base; if ((unsigned)ri < RANGE) atomicAdd(&ld[ri], w4.w);
    }
    __syncthreads();
    unsigned short* pcb = pc + (size_t)blockIdx.x * RANGE;
    float*          pdb = pd + (size_t)blockIdx.x * RANGE;
    for (int i = t; i < RANGE; i += HTHREADS) {
        pcb[i] = (unsigned short)((lc32[i >> 1] >> ((i & 1) * 16)) & 0xFFFFu);
        pdb[i] = ld[i];
    }
}

// ---- fold partials: dinv, per-slice prefix (pc in place), intra-block scan ----
__global__ __launch_bounds__(256) void reduce_kernel(
    unsigned short* __restrict__ pc, const float* __restrict__ pd,
    float* __restrict__ dinv, int* __restrict__ off, int* __restrict__ bsum)
{
    int t = threadIdx.x;
    int n = blockIdx.x * 256 + t;
    int c = 0; float d = 0.f;
    if (n < N_NODES) {
        int r = n / RANGE, i = n - r * RANGE;
        size_t base = (size_t)r * BPR * RANGE + i;
        unsigned csum = 0;
        for (int b = 0; b < BPR; ++b) {
            size_t idx = base + (size_t)b * RANGE;
            unsigned x = pc[idx];
            pc[idx] = (unsigned short)csum;
            csum += x;
            d += pd[idx];
        }
        c = (int)csum;
        dinv[n] = d > 0.f ? rsqrtf(d) : 0.f;
    }
    int lane = t & 63, wid = t >> 6;
    int v = c;
    for (int s = 1; s < 64; s <<= 1) {
        int u = __shfl_up(v, s);
        if (lane >= s) v += u;
    }
    __shared__ int ws[4];
    if (lane == 63) ws[wid] = v;
    __syncthreads();
    int wb = 0;
    for (int i = 0; i < 4; ++i) if (i < wid) wb += ws[i];
    int ex = (v - c) + wb;
    if (n < N_NODES) off[n] = ex;
    if (t == 255) bsum[blockIdx.x] = ex + c;
}

// ---- exclusive scan of 196 block sums ----
__global__ __launch_bounds__(256) void bsum_scan_kernel(
    int* __restrict__ bsum, int* __restrict__ off)
{
    int t = threadIdx.x;
    int orig = (t < NBLK) ? bsum[t] : 0;
    int lane = t & 63, wid = t >> 6;
    int v = orig;
    for (int s = 1; s < 64; s <<= 1) {
        int u = __shfl_up(v, s);
        if (lane >= s) v += u;
    }
    __shared__ int ws[4];
    if (lane == 63) ws[wid] = v;
    __syncthreads();
    int wb = 0;
    for (int i = 0; i < 4; ++i) if (i < wid) wb += ws[i];
    int ex = (v - orig) + wb;
    if (t < NBLK) bsum[t] = ex;
    if (t == NBLK - 1) off[N_NODES] = ex + orig;
}

// ---- add block prefix back ----
__global__ __launch_bounds__(256) void add_off_kernel(
    int* __restrict__ off, const int* __restrict__ bsum)
{
    int n = blockIdx.x * 256 + threadIdx.x;
    if (n < N_NODES) off[n] += bsum[n >> 8];
}

// ---- pass D: scatter via re-derived LDS ranks — zero global atomics ----
__global__ __launch_bounds__(HTHREADS) void scatter_part_kernel(
    const int* __restrict__ row, const int* __restrict__ col,
    const float* __restrict__ w, const float* __restrict__ dinv,
    const int* __restrict__ off, const unsigned short* __restrict__ pc,
    uint2* __restrict__ edges)
{
    __shared__ unsigned lc32[RANGE / 2];  // 12.5 KB
    int t = threadIdx.x;
    for (int i = t; i < RANGE / 2; i += HTHREADS) lc32[i] = 0u;
    __syncthreads();
    int r = blockIdx.x / BPR;
    int b = blockIdx.x % BPR;
    int base = r * RANGE;
    int lo = b * SLICE;
    const unsigned short* pcb = pc + (size_t)blockIdx.x * RANGE;
    for (int e0 = lo + t * 4; e0 < lo + SLICE; e0 += HTHREADS * 4) {
        int4   c4 = *(const int4*)&col[e0];
        int4   r4 = *(const int4*)&row[e0];
        float4 w4 = *(const float4*)&w[e0];
        #pragma unroll
        for (int j = 0; j < 4; ++j) {
            int c  = (j == 0) ? c4.x : (j == 1) ? c4.y : (j == 2) ? c4.z : c4.w;
            int rw = (j == 0) ? r4.x : (j == 1) ? r4.y : (j == 2) ? r4.z : r4.w;
            float we = (j == 0) ? w4.x : (j == 1) ? w4.y : (j == 2) ? w4.z : w4.w;
            int ci = c - base;
            if ((unsigned)ci < RANGE) {
                unsigned old = atomicAdd(&lc32[ci >> 1], 1u << ((ci & 1) * 16));
                unsigned lrank = (old >> ((ci & 1) * 16)) & 0xFFFFu;
                float nr = -dinv[rw] * we * dinv[c];
                int pos = off[c] + (int)pcb[ci] + (int)lrank;
                edges[pos] = make_uint2((unsigned)rw, __float_as_uint(nr));
            }
        }
    }
}

// ---- MFMA xf: xf = relu(x @ W_in + b_in), one wave per 16-node tile ----
__global__ __launch_bounds__(256) void xf_mfma_kernel(
    const float* __restrict__ x, const float* __restrict__ Win,
    const float* __restrict__ bin, float* __restrict__ xf_out,
    __half* __restrict__ T0h)
{
    __shared__ half8 Wf[3][4][64];   // 12288 B
    __shared__ float bs[EMB];
    int t = threadIdx.x;
    for (int idx = t; idx < 3 * 4 * 64; idx += 256) {
        int j = idx >> 8;
        int rem = idx & 255;
        int s = rem >> 6;
        int l = rem & 63;
        int colw = j * 16 + (l & 15);
        int k0 = s * 32 + (l >> 4) * 8;
        half8 v;
        #pragma unroll
        for (int i = 0; i < 8; ++i)
            v[i] = (_Float16)Win[(k0 + i) * EMB + colw];
        Wf[j][s][l] = v;
    }
    if (t < EMB) bs[t] = bin[t];
    __syncthreads();

    int wid = t >> 6, lane = t & 63;
    int nt = blockIdx.x * 4 + wid;
    if (nt >= NTILES) return;
    int n0 = nt * 16;
    int arow = lane & 15, kg = lane >> 4;

    const float* xr = x + (size_t)(n0 + arow) * F_IN + kg * 8;
    half8 a[4];
    #pragma unroll
    for (int s = 0; s < 4; ++s) {
        f32x4 lo = *reinterpret_cast<const f32x4*>(xr + s * 32);
        f32x4 hi = *reinterpret_cast<const f32x4*>(xr + s * 32 + 4);
        half8 av;
        av[0] = (_Float16)lo[0]; av[1] = (_Float16)lo[1];
        av[2] = (_Float16)lo[2]; av[3] = (_Float16)lo[3];
        av[4] = (_Float16)hi[0]; av[5] = (_Float16)hi[1];
        av[6] = (_Float16)hi[2]; av[7] = (_Float16)hi[3];
        a[s] = av;
    }

    f32x4 c0 = {0.f, 0.f, 0.f, 0.f}, c1 = c0, c2 = c0;
    #pragma unroll
    for (int s = 0; s < 4; ++s) {
        c0 = __builtin_amdgcn_mfma_f32_16x16x32_f16(a[s], Wf[0][s][lane], c0, 0, 0, 0);
        c1 = __builtin_amdgcn_mfma_f32_16x16x32_f16(a[s], Wf[1][s][lane], c1, 0, 0, 0);
        c2 = __builtin_amdgcn_mfma_f32_16x16x32_f16(a[s], Wf[2][s][lane], c2, 0, 0, 0);
    }

    int ccol = lane & 15;
    #pragma unroll
    for (int j = 0; j < 3; ++j) {
        int colg = j * 16 + ccol;
        float bias = bs[colg];
        f32x4 cj = (j == 0) ? c0 : (j == 1) ? c1 : c2;
        #pragma unroll
        for (int r = 0; r < 4; ++r) {
            int n = n0 + kg * 4 + r;
            float v = fmaxf(cj[r] + bias, 0.f);
            xf_out[(size_t)n * EMB + colg] = v;
            T0h[(size_t)n * TPAD + colg] = __float2half_rn(v);
        }
    }
    {
        int n = n0 + (lane >> 2);
        int cp = 48 + (lane & 3) * 4;
        *reinterpret_cast<uint2*>(T0h + (size_t)n * TPAD + cp) = make_uint2(0u, 0u);
    }
}

// ---- k=1 prop: T1 = prop(T0); out_acc = T0@W0 + T1@W1 (pure write) ----
// Barrier only after weight staging; gather->epilogue is wave-local (no straggler wait).
__global__ __launch_bounds__(256) void prop_k1_kernel(
    const int* __restrict__ off, const uint2* __restrict__ edges,
    const __half* __restrict__ T0, __half* __restrict__ T1,
    const float* __restrict__ W0, const float* __restrict__ W1,
    float* __restrict__ out_acc)
{
    __shared__ float W0s[EMB * HID];    // 9216 B
    __shared__ float W1s[EMB * HID];    // 9216 B
    __shared__ float tdS[16][EMB + 1];
    __shared__ float t0S[16][EMB + 1];
    int t = threadIdx.x;
    for (int i = t; i < EMB * HID; i += 256) { W0s[i] = W0[i]; W1s[i] = W1[i]; }
    __syncthreads();   // covers weight staging only

    int grp = t >> 4, lane = t & 15;
    int g = blockIdx.x * 16 + grp;

    float a0 = 0.f, a1 = 0.f, a2 = 0.f, a3 = 0.f;
    if (lane < 12) {
        int s = off[g], e = off[g + 1];
        int p = s;
        PROP_GATHER_LOOP(T0)
        uint2 tv = *reinterpret_cast<const uint2*>(T0 + (size_t)g * TPAD + 4 * lane);
        __half2 t01 = *reinterpret_cast<__half2*>(&tv.x);
        __half2 t23 = *reinterpret_cast<__half2*>(&tv.y);
        t0S[grp][4 * lane]     = __low2float(t01);
        t0S[grp][4 * lane + 1] = __high2float(t01);
        t0S[grp][4 * lane + 2] = __low2float(t23);
        t0S[grp][4 * lane + 3] = __high2float(t23);
        tdS[grp][4 * lane]     = a0;
        tdS[grp][4 * lane + 1] = a1;
        tdS[grp][4 * lane + 2] = a2;
        tdS[grp][4 * lane + 3] = a3;
    }
    {
        __half2 h01, h23;
        h01.x = __float2half_rn(a0); h01.y = __float2half_rn(a1);
        h23.x = __float2half_rn(a2); h23.y = __float2half_rn(a3);
        uint2 ov;
        ov.x = *reinterpret_cast<unsigned*>(&h01);
        ov.y = *reinterpret_cast<unsigned*>(&h23);
        *reinterpret_cast<uint2*>(T1 + (size_t)g * TPAD + 4 * lane) = ov;
    }
    // tdS/t0S rows are wave-local (4 groups per wave) — no barrier needed

    float o0 = 0.f, o1 = 0.f, o2 = 0.f;
#pragma unroll 8
    for (int c = 0; c < EMB; ++c) {
        float t1v = tdS[grp][c];
        float t0v = t0S[grp][c];
        o0 += t1v * W1s[c * HID + lane]      + t0v * W0s[c * HID + lane];
        o1 += t1v * W1s[c * HID + lane + 16] + t0v * W0s[c * HID + lane + 16];
        o2 += t1v * W1s[c * HID + lane + 32] + t0v * W0s[c * HID + lane + 32];
    }
    float* orow = out_acc + (size_t)g * HID;
    orow[lane]      = o0;
    orow[lane + 16] = o1;
    orow[lane + 32] = o2;
}

// ---- k=2..5: T_k = 2*prop(T_{k-1}) - T_{k-2}; out_acc += T_k @ W_k ----
__global__ __launch_bounds__(256) void prop_fused_kernel(
    const int* __restrict__ off, const uint2* __restrict__ edges,
    const __half* __restrict__ tsrc, const __half* __restrict__ tprev,
    __half* __restrict__ tdst, const float* __restrict__ Wk,
    float* __restrict__ out_acc)
{
    __shared__ float Ws[EMB * HID];     // 9216 B
    __shared__ float tdS[16][EMB + 1];
    int t = threadIdx.x;
    for (int i = t; i < EMB * HID; i += 256) Ws[i] = Wk[i];
    __syncthreads();   // covers weight staging only

    int grp = t >> 4, lane = t & 15;
    int g = blockIdx.x * 16 + grp;

    float a0 = 0.f, a1 = 0.f, a2 = 0.f, a3 = 0.f;
    if (lane < 12) {
        int s = off[g], e = off[g + 1];
        int p = s;
        PROP_GATHER_LOOP(tsrc)
        uint2 tv = *reinterpret_cast<const uint2*>(tprev + (size_t)g * TPAD + 4 * lane);
        __half2 t01 = *reinterpret_cast<__half2*>(&tv.x);
        __half2 t23 = *reinterpret_cast<__half2*>(&tv.y);
        a0 = 2.f * a0 - __low2float(t01);
        a1 = 2.f * a1 - __high2float(t01);
        a2 = 2.f * a2 - __low2float(t23);
        a3 = 2.f * a3 - __high2float(t23);
        tdS[grp][4 * lane]     = a0;
        tdS[grp][4 * lane + 1] = a1;
        tdS[grp][4 * lane + 2] = a2;
        tdS[grp][4 * lane + 3] = a3;
    }
    {
        __half2 h01, h23;
        h01.x = __float2half_rn(a0); h01.y = __float2half_rn(a1);
        h23.x = __float2half_rn(a2); h23.y = __float2half_rn(a3);
        uint2 ov;
        ov.x = *reinterpret_cast<unsigned*>(&h01);
        ov.y = *reinterpret_cast<unsigned*>(&h23);
        *reinterpret_cast<uint2*>(tdst + (size_t)g * TPAD + 4 * lane) = ov;
    }
    // tdS row is wave-local — no barrier needed

    float o0 = 0.f, o1 = 0.f, o2 = 0.f;
#pragma unroll 8
    for (int c = 0; c < EMB; ++c) {
        float tv = tdS[grp][c];
        o0 += tv * Ws[c * HID + lane];
        o1 += tv * Ws[c * HID + lane + 16];
        o2 += tv * Ws[c * HID + lane + 32];
    }
    float* orow = out_acc + (size_t)g * HID;
    orow[lane]      += o0;
    orow[lane + 16] += o1;
    orow[lane + 32] += o2;
}

// ---- k=6 prop fused with final: y = relu(out_acc + T6@W6 + b_cheb) @ W_out + b_out ----
__global__ __launch_bounds__(256) void prop_final_kernel(
    const int* __restrict__ off, const uint2* __restrict__ edges,
    const __half* __restrict__ tsrc, const __half* __restrict__ tprev,
    const float* __restrict__ Wk, const float* __restrict__ out_acc,
    const float* __restrict__ bch, const float* __restrict__ Wout,
    const float* __restrict__ bout, float* __restrict__ y)
{
    __shared__ float Ws[EMB * HID];      // 9216 B
    __shared__ float Wo[HID * OUTF];     // 12288 B
    __shared__ float tdS[16][EMB + 1];
    __shared__ float vS[16][HID + 1];
    __shared__ float bchS[HID];
    __shared__ float boS[OUTF];
    int t = threadIdx.x;
    for (int i = t; i < EMB * HID; i += 256) Ws[i] = Wk[i];
    for (int i = t; i < HID * OUTF; i += 256) Wo[i] = Wout[i];
    if (t < HID) bchS[t] = bch[t];
    if (t < OUTF) boS[t] = bout[t];
    __syncthreads();   // covers weight/bias staging only

    int grp = t >> 4, lane = t & 15;
    int g = blockIdx.x * 16 + grp;

    float a0 = 0.f, a1 = 0.f, a2 = 0.f, a3 = 0.f;
    if (lane < 12) {
        int s = off[g], e = off[g + 1];
        int p = s;
        PROP_GATHER_LOOP(tsrc)
        uint2 tv = *reinterpret_cast<const uint2*>(tprev + (size_t)g * TPAD + 4 * lane);
        __half2 t01 = *reinterpret_cast<__half2*>(&tv.x);
        __half2 t23 = *reinterpret_cast<__half2*>(&tv.y);
        a0 = 2.f * a0 - __low2float(t01);
        a1 = 2.f * a1 - __high2float(t01);
        a2 = 2.f * a2 - __low2float(t23);
        a3 = 2.f * a3 - __high2float(t23);
        tdS[grp][4 * lane]     = a0;
        tdS[grp][4 * lane + 1] = a1;
        tdS[grp][4 * lane + 2] = a2;
        tdS[grp][4 * lane + 3] = a3;
    }
    // tdS/vS rows are wave-local — no barrier needed

    float o0 = 0.f, o1 = 0.f, o2 = 0.f;
#pragma unroll 8
    for (int c = 0; c < EMB; ++c) {
        float tv = tdS[grp][c];
        o0 += tv * Ws[c * HID + lane];
        o1 += tv * Ws[c * HID + lane + 16];
        o2 += tv * Ws[c * HID + lane + 32];
    }
    const float* orow = out_acc + (size_t)g * HID;
    vS[grp][lane]      = fmaxf(orow[lane]      + o0 + bchS[lane],      0.f);
    vS[grp][lane + 16] = fmaxf(orow[lane + 16] + o1 + bchS[lane + 16], 0.f);
    vS[grp][lane + 32] = fmaxf(orow[lane + 32] + o2 + bchS[lane + 32], 0.f);

    float y0 = boS[4 * lane], y1 = boS[4 * lane + 1];
    float y2 = boS[4 * lane + 2], y3 = boS[4 * lane + 3];
#pragma unroll 8
    for (int h = 0; h < HID; ++h) {
        float v = vS[grp][h];
        float4 w4 = *reinterpret_cast<const float4*>(&Wo[h * OUTF + 4 * lane]);
        y0 += v * w4.x; y1 += v * w4.y; y2 += v * w4.z; y3 += v * w4.w;
    }
    *reinterpret_cast<float4*>(y + (size_t)g * OUTF + 4 * lane) =
        make_float4(y0, y1, y2, y3);
}

extern "C" void kernel_launch(void* const* d_in, const int* in_sizes, int n_in,
                              void* d_out, int out_size, void* d_ws, size_t ws_size,
                              hipStream_t stream)
{
    const float* x    = (const float*)d_in[0];
    const int*   ei   = (const int*)d_in[1];
    const float* ew   = (const float*)d_in[2];
    const float* Win  = (const float*)d_in[3];
    const float* bin  = (const float*)d_in[4];
    const float* Wch  = (const float*)d_in[5];   // [7,48,48]
    const float* bch  = (const float*)d_in[6];
    const float* Wout = (const float*)d_in[7];
    const float* bout = (const float*)d_in[8];

    const int* row = ei;
    const int* col = ei + N_EDGES;

    float* y_out  = (float*)d_out;                           // [N,64]
    float* xf_out = (float*)d_out + (size_t)N_NODES * OUTF;  // [N,48]

    char* p = (char*)d_ws;
    auto carve = [&](size_t bytes) {
        void* q = p;
        p += (bytes + 255) & ~(size_t)255;
        return q;
    };
    unsigned short* pc = (unsigned short*)carve((size_t)NR * BPR * RANGE * 2); // 6.4 MB
    float*    pd  = (float*)carve((size_t)NR * BPR * RANGE * 4);               // 12.8 MB
    float*    dinv = (float*)carve(N_NODES * 4);
    int*      off  = (int*)  carve((N_NODES + 1) * 4);
    int*      bsum = (int*)  carve(NBLK * 4);
    uint2*    edges = (uint2*)carve((size_t)N_EDGES * 8);
    float*    out_acc = (float*)carve((size_t)N_NODES * HID * 4);
    __half*   T0h = (__half*)carve((size_t)N_NODES * TPAD * 2);   // 6.4 MB each
    __half*   TAh = (__half*)carve((size_t)N_NODES * TPAD * 2);
    __half*   TBh = (__half*)carve((size_t)N_NODES * TPAD * 2);
    __half*   TCh = (__half*)carve((size_t)N_NODES * TPAD * 2);

    // graph preprocessing — zero global atomics, hierarchical scan
    hist_part_kernel<<<NR * BPR, HTHREADS, 0, stream>>>(row, col, ew, pc, pd);
    reduce_kernel<<<NBLK, 256, 0, stream>>>(pc, pd, dinv, off, bsum);
    bsum_scan_kernel<<<1, 256, 0, stream>>>(bsum, off);
    add_off_kernel<<<NBLK, 256, 0, stream>>>(off, bsum);
    scatter_part_kernel<<<NR * BPR, HTHREADS, 0, stream>>>(row, col, ew, dinv, off, pc, edges);

    // xf via MFMA -> f32 d_out tail + padded fp16 T0
    xf_mfma_kernel<<<(NTILES + 3) / 4, 256, 0, stream>>>(x, Win, bin, xf_out, T0h);

    const int prop_grid = NTILES;   // 3125

    // k=1: T1 = prop(T0); out_acc = T0@W0 + T1@W1 (write)
    prop_k1_kernel<<<prop_grid, 256, 0, stream>>>(off, edges, T0h, TAh,
                                                  Wch, Wch + EMB * HID, out_acc);
    // k=2..5 with fused GEMM — proven 3-buffer rotation.
    const __half* A = T0h;  // T_{k-2}
    __half*       B = TAh;  // T_{k-1}
    __half* bufs[3] = {TBh, TCh, TAh};
    for (int k = 2; k < KCH - 1; ++k) {
        __half* C = bufs[(k - 2) % 3];
        prop_fused_kernel<<<prop_grid, 256, 0, stream>>>(off, edges, B, A,
                                                         C, Wch + (size_t)k * EMB * HID, out_acc);
        A = B; B = C;
    }
    // k=6: fused prop + final
    prop_final_kernel<<<prop_grid, 256, 0, stream>>>(off, edges, B, A,
                                                     Wch + (size_t)(KCH - 1) * EMB * HID,
                                                     out_acc, bch, Wout, bout, y_out);
}